// Round 1
// baseline (3224.852 us; speedup 1.0000x reference)
//
#include <hip/hip_runtime.h>
#include <math.h>

// Problem constants (from reference)
#define NB   128   // batch (documents)
#define NS   40    // sentences per doc
#define NW   50    // words per sentence
#define ED   200   // embedding dim == 2*HW == 2*HS (all 200 here)
#define NHW  100   // hidden per direction
#define FEAT 200   // 2*HW = 2*HS
#define NC   10

// -------------------------------------------------------------------------
// Shared encoder: one-timestep bidirectional GRU (zero hidden state) +
// additive attention softmax. Operates on LDS-resident input e_sh
// ([NWRD][ED]) and writes h_sh ([NWRD][FEAT]) and alpha into sc_sh.
// e_sh is DEAD after the GRU phase and is reused as the u-partial matrix
// (u[d][w], FEAT*NWRD floats) for the attention score reduction.
//
// Thread->work mapping: item = (unit, word-group); each thread computes the
// 3 gate dot-products (r,z,n rows) for its unit over WT words. All lanes of
// a wave share the same word-group -> LDS e reads are broadcast
// (conflict-free). Weight rows stream from global (480 KB, L2-resident).
// -------------------------------------------------------------------------
template<int NWRD, int WT>
__device__ __forceinline__ void encode_block(
    float* __restrict__ e_sh, float* __restrict__ h_sh, float* __restrict__ sc_sh,
    const float* __restrict__ Wf, const float* __restrict__ bihf, const float* __restrict__ bhhf,
    const float* __restrict__ Wb, const float* __restrict__ bihb, const float* __restrict__ bhhb,
    const float* __restrict__ aW, const float* __restrict__ ab, const float* __restrict__ actx,
    int tid)
{
    constexpr int WG = NWRD / WT;   // word groups (2)

    // ---- Phase 1: GRU gates + combine -> h_sh ----
    for (int item = tid; item < FEAT * WG; item += 256) {
        const int unit = item % FEAT;
        const int wg   = item / FEAT;
        const int dir  = unit / NHW;
        const int j    = unit - dir * NHW;
        const float* Wd  = dir ? Wb  : Wf;
        const float* bih = dir ? bihb : bihf;
        const float* bhh = dir ? bhhb : bhhf;
        const float4* rowR = (const float4*)(Wd + (size_t)j * ED);
        const float4* rowZ = (const float4*)(Wd + (size_t)(NHW + j) * ED);
        const float4* rowN = (const float4*)(Wd + (size_t)(2 * NHW + j) * ED);

        float aR[WT], aZ[WT], aN[WT];
        #pragma unroll
        for (int t = 0; t < WT; ++t) { aR[t] = 0.f; aZ[t] = 0.f; aN[t] = 0.f; }

        const int w0 = wg * WT;
        #pragma unroll 1
        for (int k4 = 0; k4 < ED / 4; ++k4) {
            const float4 wr = rowR[k4];
            const float4 wz = rowZ[k4];
            const float4 wn = rowN[k4];
            #pragma unroll
            for (int t = 0; t < WT; ++t) {
                const float4 e = *(const float4*)(e_sh + (w0 + t) * ED + k4 * 4);
                aR[t] += wr.x * e.x; aR[t] += wr.y * e.y; aR[t] += wr.z * e.z; aR[t] += wr.w * e.w;
                aZ[t] += wz.x * e.x; aZ[t] += wz.y * e.y; aZ[t] += wz.z * e.z; aZ[t] += wz.w * e.w;
                aN[t] += wn.x * e.x; aN[t] += wn.y * e.y; aN[t] += wn.z * e.z; aN[t] += wn.w * e.w;
            }
        }
        const float bR = bih[j] + bhh[j];
        const float bZ = bih[NHW + j] + bhh[NHW + j];
        const float bN = bih[2 * NHW + j];
        const float hN = bhh[2 * NHW + j];
        #pragma unroll
        for (int t = 0; t < WT; ++t) {
            const float r = 1.f / (1.f + __expf(-(aR[t] + bR)));
            const float z = 1.f / (1.f + __expf(-(aZ[t] + bZ)));
            const float nv = aN[t] + bN + r * hN;
            const float ex = __expf(2.f * nv);
            const float n = (ex - 1.f) / (ex + 1.f);     // tanh
            h_sh[(w0 + t) * FEAT + unit] = (1.f - z) * n;
        }
    }
    __syncthreads();

    // ---- Phase 2: attention score partials u[d][w] = tanh(h.Wa_d + b_d)*ctx_d
    //      (reuses e_sh as u storage: FEAT*NWRD floats) ----
    for (int item = tid; item < FEAT * WG; item += 256) {
        const int d  = item % FEAT;
        const int wg = item / FEAT;
        const float4* row = (const float4*)(aW + (size_t)d * FEAT);
        float acc[WT];
        #pragma unroll
        for (int t = 0; t < WT; ++t) acc[t] = 0.f;
        const int w0 = wg * WT;
        #pragma unroll 1
        for (int k4 = 0; k4 < FEAT / 4; ++k4) {
            const float4 wv = row[k4];
            #pragma unroll
            for (int t = 0; t < WT; ++t) {
                const float4 h = *(const float4*)(h_sh + (w0 + t) * FEAT + k4 * 4);
                acc[t] += wv.x * h.x; acc[t] += wv.y * h.y; acc[t] += wv.z * h.z; acc[t] += wv.w * h.w;
            }
        }
        const float bb = ab[d], cc = actx[d];
        #pragma unroll
        for (int t = 0; t < WT; ++t) {
            const float v = acc[t] + bb;
            const float ex = __expf(2.f * v);
            e_sh[d * NWRD + (w0 + t)] = ((ex - 1.f) / (ex + 1.f)) * cc;
        }
    }
    __syncthreads();

    // ---- Phase 3: reduce scores over d, softmax over words ----
    if (tid < NWRD) {
        float s = 0.f;
        for (int d = 0; d < FEAT; ++d) s += e_sh[d * NWRD + tid];
        sc_sh[tid] = s;
    }
    __syncthreads();
    if (tid == 0) {
        float m = -1e30f;
        for (int w = 0; w < NWRD; ++w) m = fmaxf(m, sc_sh[w]);
        float s = 0.f;
        for (int w = 0; w < NWRD; ++w) { const float ev = __expf(sc_sh[w] - m); sc_sh[w] = ev; s += ev; }
        const float inv = 1.f / s;
        for (int w = 0; w < NWRD; ++w) sc_sh[w] *= inv;
    }
    __syncthreads();
}

// -------------------------------------------------------------------------
// Kernel 1: word-level encoder+attention, one block per sentence (5120).
// Writes svec [B*S][FEAT] fp32 to workspace.
// -------------------------------------------------------------------------
__global__ __launch_bounds__(256) void word_kernel(
    const int* __restrict__ x, const float* __restrict__ emb,
    const float* __restrict__ Wf, const float* __restrict__ bihf, const float* __restrict__ bhhf,
    const float* __restrict__ Wb, const float* __restrict__ bihb, const float* __restrict__ bhhb,
    const float* __restrict__ waW, const float* __restrict__ wab, const float* __restrict__ wactx,
    float* __restrict__ svec)
{
    __shared__ __align__(16) float e_sh[NW * ED];    // 40 KB (reused as u)
    __shared__ __align__(16) float h_sh[NW * FEAT];  // 40 KB wenc
    __shared__ float sc_sh[NW];

    const int sent = blockIdx.x;          // b*NS + s
    const int tid  = threadIdx.x;
    const int* xr  = x + (size_t)sent * NW;

    // gather embeddings -> LDS (float4, coalesced within rows)
    for (int i = tid * 4; i < NW * ED; i += 256 * 4) {
        const int w = i / ED;
        const int k = i - w * ED;
        const size_t tok = (size_t)xr[w];
        *(float4*)(e_sh + i) = *(const float4*)(emb + tok * ED + k);
    }
    __syncthreads();

    encode_block<NW, 25>(e_sh, h_sh, sc_sh,
                         Wf, bihf, bhhf, Wb, bihb, bhhb,
                         waW, wab, wactx, tid);

    // pooled sentence vector
    if (tid < FEAT) {
        float a = 0.f;
        #pragma unroll 1
        for (int w = 0; w < NW; ++w) a += sc_sh[w] * h_sh[w * FEAT + tid];
        svec[(size_t)sent * FEAT + tid] = a;
    }
}

// -------------------------------------------------------------------------
// Kernel 2: sentence-level encoder+attention+classifier, one block per doc.
// -------------------------------------------------------------------------
__global__ __launch_bounds__(256) void sent_kernel(
    const float* __restrict__ svec,
    const float* __restrict__ Wf, const float* __restrict__ bihf, const float* __restrict__ bhhf,
    const float* __restrict__ Wb, const float* __restrict__ bihb, const float* __restrict__ bhhb,
    const float* __restrict__ saW, const float* __restrict__ sab, const float* __restrict__ sactx,
    const float* __restrict__ fcW, const float* __restrict__ fcb,
    float* __restrict__ out)
{
    __shared__ __align__(16) float e_sh[NS * ED];    // 32 KB (reused as u)
    __shared__ __align__(16) float h_sh[NS * FEAT];  // 32 KB senc
    __shared__ float sc_sh[NS];
    __shared__ float dvec_sh[FEAT];
    __shared__ float logit_sh[NC];
    __shared__ float lse_sh;

    const int b   = blockIdx.x;
    const int tid = threadIdx.x;
    const float* src = svec + (size_t)b * NS * FEAT;

    for (int i = tid * 4; i < NS * FEAT; i += 256 * 4)
        *(float4*)(e_sh + i) = *(const float4*)(src + i);
    __syncthreads();

    encode_block<NS, 20>(e_sh, h_sh, sc_sh,
                         Wf, bihf, bhhf, Wb, bihb, bhhb,
                         saW, sab, sactx, tid);

    if (tid < FEAT) {
        float a = 0.f;
        #pragma unroll 1
        for (int s = 0; s < NS; ++s) a += sc_sh[s] * h_sh[s * FEAT + tid];
        dvec_sh[tid] = a;
    }
    __syncthreads();

    if (tid < NC) {
        float a = fcb[tid];
        const float* row = fcW + (size_t)tid * FEAT;
        for (int k = 0; k < FEAT; ++k) a += row[k] * dvec_sh[k];
        logit_sh[tid] = a;
    }
    __syncthreads();
    if (tid == 0) {
        float m = -1e30f;
        for (int c = 0; c < NC; ++c) m = fmaxf(m, logit_sh[c]);
        float s = 0.f;
        for (int c = 0; c < NC; ++c) s += __expf(logit_sh[c] - m);
        lse_sh = m + logf(s);
    }
    __syncthreads();
    if (tid < NC) out[(size_t)b * NC + tid] = logit_sh[tid] - lse_sh;
}

extern "C" void kernel_launch(void* const* d_in, const int* in_sizes, int n_in,
                              void* d_out, int out_size, void* d_ws, size_t ws_size,
                              hipStream_t stream)
{
    const int*   x     = (const int*)d_in[0];
    const float* emb   = (const float*)d_in[1];
    const float* wWf   = (const float*)d_in[2];
    const float* wbif  = (const float*)d_in[3];
    const float* wbhf  = (const float*)d_in[4];
    const float* wWb   = (const float*)d_in[5];
    const float* wbib  = (const float*)d_in[6];
    const float* wbhb  = (const float*)d_in[7];
    const float* waW   = (const float*)d_in[8];
    const float* wab   = (const float*)d_in[9];
    const float* wactx = (const float*)d_in[10];
    const float* sWf   = (const float*)d_in[11];
    const float* sbif  = (const float*)d_in[12];
    const float* sbhf  = (const float*)d_in[13];
    const float* sWb   = (const float*)d_in[14];
    const float* sbib  = (const float*)d_in[15];
    const float* sbhb  = (const float*)d_in[16];
    const float* saW   = (const float*)d_in[17];
    const float* sab   = (const float*)d_in[18];
    const float* sactx = (const float*)d_in[19];
    const float* fcW   = (const float*)d_in[20];
    const float* fcb   = (const float*)d_in[21];

    float* out  = (float*)d_out;
    float* svec = (float*)d_ws;   // [NB*NS][FEAT] fp32 = 4.10 MB

    word_kernel<<<NB * NS, 256, 0, stream>>>(
        x, emb, wWf, wbif, wbhf, wWb, wbib, wbhb, waW, wab, wactx, svec);
    sent_kernel<<<NB, 256, 0, stream>>>(
        svec, sWf, sbif, sbhf, sWb, sbib, sbhb, saW, sab, sactx, fcW, fcb, out);
}

// Round 2
// 471.149 us; speedup vs baseline: 6.8447x; 6.8447x over previous
//
#include <hip/hip_runtime.h>
#include <math.h>

// ============================ problem constants ============================
#define NB   128
#define NS   40
#define NW   50
#define ED   200   // = 2*HW = 2*HS
#define NHW  100
#define FEAT 200
#define NC   10
#define MWORD (NB*NS*NW)   // 256000 word rows
#define MSENT (NB*NS)      // 5120 sentence rows

// ============================ ws memory map (bytes) ========================
#define GRU_BLOB 21760ull            // 48*224*2 bf16 + 64 fp32 bias
#define ATT_BLOB 21888ull            // 48*224*2 bf16 + 48+48 fp32 (ab, ctx)
#define OFF_ZPAD 0ull
#define OFF_PGW  512ull
#define OFF_PAW  (OFF_PGW + 14ull*GRU_BLOB)     // 305,152
#define OFF_PGS  (OFF_PAW + 5ull*ATT_BLOB)      // 414,592
#define OFF_PAS  (OFF_PGS + 14ull*GRU_BLOB)     // 719,232
#define OFF_EMB  829440ull                      // emb bf16 [100000][200]
#define OFF_HW   (OFF_EMB + 40000000ull)        // H word [256000][200] bf16
#define OFF_SV   (OFF_HW + 102400000ull)        // svec [5120][200] bf16
#define OFF_HS   (OFF_SV + 2048000ull)          // H sent [5120][200] bf16
#define OFF_DV   (OFF_HS + 2048000ull)          // dvec [128][200] bf16
#define WS_NEED  (OFF_DV + 51200ull)            // 147,376,640 B

// ============================ helpers ======================================
typedef short bf16x8 __attribute__((ext_vector_type(8)));
typedef float f32x4  __attribute__((ext_vector_type(4)));

__device__ __forceinline__ unsigned short f2bf(float f) {
    unsigned int u = __float_as_uint(f);
    u += 0x7fffu + ((u >> 16) & 1u);          // RNE
    return (unsigned short)(u >> 16);
}
__device__ __forceinline__ float bf2f_lo(unsigned int u) { return __uint_as_float(u << 16); }
__device__ __forceinline__ float bf2f_hi(unsigned int u) { return __uint_as_float(u & 0xffff0000u); }
__device__ __forceinline__ float frcp(float x) { return __builtin_amdgcn_rcpf(x); }
__device__ __forceinline__ float fsig(float x) { return frcp(1.f + __expf(-x)); }
__device__ __forceinline__ float ftanh(float x){ return 1.f - 2.f*frcp(1.f + __expf(2.f*x)); }

// async global->LDS, 16B per lane. LDS side must be contiguous per lane.
__device__ __forceinline__ void gld16(const void* g, void* l) {
    __builtin_amdgcn_global_load_lds(
        (const __attribute__((address_space(1))) void*)g,
        (__attribute__((address_space(3))) void*)l, 16, 0, 0);
}

// ============================ P1: weight packing ===========================
// blocks 0..13: word GRU chunks (dir*7+c); 14..18: word attn; 19..32 sent GRU;
// 33..37 sent attn; 38: zero pad region.
// GRU blob: rows 0..15 = r-gate units [c*16..), 16..31 = z, 32..47 = n;
// cols 0..223 (K zero-padded); then 64 fp32: bR[16], bZ[16], bN[16], hN[16].
__global__ void pack_kernel(
    const float* __restrict__ wWf, const float* __restrict__ wbif, const float* __restrict__ wbhf,
    const float* __restrict__ wWb, const float* __restrict__ wbib, const float* __restrict__ wbhb,
    const float* __restrict__ waW, const float* __restrict__ wab, const float* __restrict__ wactx,
    const float* __restrict__ sWf, const float* __restrict__ sbif, const float* __restrict__ sbhf,
    const float* __restrict__ sWb, const float* __restrict__ sbib, const float* __restrict__ sbhb,
    const float* __restrict__ saW, const float* __restrict__ sab, const float* __restrict__ sactx,
    char* __restrict__ ws)
{
    const int b = blockIdx.x, tid = threadIdx.x;
    if (b == 38) { if (tid < 128) ((float*)(ws + OFF_ZPAD))[tid] = 0.f; return; }
    const bool word = b < 19;
    const int lb = word ? b : b - 19;
    if (lb < 14) {
        const int dir = lb / 7, c = lb % 7;
        const float* W   = word ? (dir ? wWb : wWf) : (dir ? sWb : sWf);
        const float* bih = word ? (dir ? wbib : wbif) : (dir ? sbib : sbif);
        const float* bhh = word ? (dir ? wbhb : wbhf) : (dir ? sbhb : sbhf);
        char* blob = ws + (word ? OFF_PGW : OFF_PGS) + (size_t)lb * GRU_BLOB;
        unsigned short* dst = (unsigned short*)blob;
        for (int e = tid; e < 48 * 224; e += 256) {
            const int row = e / 224, k = e - row * 224;
            const int g = row >> 4, j = c * 16 + (row & 15);
            const float v = (j < NHW && k < ED) ? W[(size_t)(g * NHW + j) * ED + k] : 0.f;
            dst[e] = f2bf(v);
        }
        if (tid < 64) {
            const int sect = tid >> 4, j = c * 16 + (tid & 15);
            float v = 0.f;
            if (j < NHW) {
                if (sect == 0)      v = bih[j] + bhh[j];
                else if (sect == 1) v = bih[NHW + j] + bhh[NHW + j];
                else if (sect == 2) v = bih[2 * NHW + j];
                else                v = bhh[2 * NHW + j];
            }
            ((float*)(blob + 21504))[tid] = v;
        }
    } else {
        const int c = lb - 14;
        const float* W  = word ? waW : saW;
        const float* ab = word ? wab : sab;
        const float* cx = word ? wactx : sactx;
        char* blob = ws + (word ? OFF_PAW : OFF_PAS) + (size_t)c * ATT_BLOB;
        unsigned short* dst = (unsigned short*)blob;
        for (int e = tid; e < 48 * 224; e += 256) {
            const int row = e / 224, k = e - row * 224;
            const int d = c * 48 + row;
            const float v = (d < FEAT && k < FEAT) ? W[(size_t)d * FEAT + k] : 0.f;
            dst[e] = f2bf(v);
        }
        if (tid < 48) {
            const int d = c * 48 + tid;
            ((float*)(blob + 21504))[tid] = (d < FEAT) ? ab[d] : 0.f;
            ((float*)(blob + 21696))[tid] = (d < FEAT) ? cx[d] : 0.f;
        }
    }
}

// ============================ P2: emb -> bf16 ==============================
__global__ void embcvt_kernel(const float* __restrict__ emb, unsigned short* __restrict__ dst)
{
    const long i = (long)blockIdx.x * 256 + threadIdx.x;   // float4 groups
    if (i < 5000000) {
        const float4 v = ((const float4*)emb)[i];
        ushort4 o;
        o.x = f2bf(v.x); o.y = f2bf(v.y); o.z = f2bf(v.z); o.w = f2bf(v.w);
        ((ushort4*)dst)[i] = o;
    }
}

// ============================ K2: bigru0 GEMM ==============================
// Block: 256 rows, 256 thr (4 waves); wave owns 64 rows = 4 M-tiles.
// A-fragments (4 Mt x 7 kc b128) live in registers across all 14 chunks;
// B (48x224 bf16 + bias) double-buffered in LDS via global_load_lds.
// MFMA 16x16x32 bf16; C layout col=lane&15 (unit), row=(lane>>4)*4+reg.
template<bool GATHER>
__global__ __launch_bounds__(256, 1) void gru_kernel(
    const int* __restrict__ xtok,      // GATHER: token per row
    const char* __restrict__ abase,    // GATHER: emb_bf; else bf16 rows [.][400 B]
    const char* __restrict__ packs,    // 14 GRU blobs
    const char* __restrict__ zp,       // 512 B zeros
    unsigned short* __restrict__ Hout) // [M][200] bf16
{
    __shared__ __align__(16) char smem[114688 + 1024];
    char* Ash = smem;                          // [256][448 B]; dead after frag loads
    int*  xsh = (int*)(smem + 114688);
    char* buf0 = smem;                         // B dbuf aliases A area
    char* buf1 = smem + 21760;

    const int tid = threadIdx.x;
    const int lane = tid & 63, wv = tid >> 6;
    const int ln15 = lane & 15, g16 = (lane >> 4) * 16;
    const long rowbase = (long)blockIdx.x * 256;

    if (GATHER) { xsh[tid] = xtok[rowbase + tid]; __syncthreads(); }

    // ---- stage A: 256 rows x 28 16B-units (25 data + 3 zero) ----
    for (int t = tid; t < 7168; t += 256) {
        const int r = t / 28, u = t - r * 28;
        const char* src = zp;
        if (u < 25) {
            const long rid = GATHER ? (long)xsh[r] : (rowbase + r);
            src = abase + rid * 400 + (long)u * 16;
        }
        gld16(src, Ash + (size_t)t * 16);
    }
    __syncthreads();

    // ---- A fragments into registers ----
    bf16x8 af[4][7];
    #pragma unroll
    for (int Mt = 0; Mt < 4; ++Mt)
        #pragma unroll
        for (int kc = 0; kc < 7; ++kc)
            af[Mt][kc] = *(const bf16x8*)(Ash + (size_t)(wv * 64 + Mt * 16 + ln15) * 448 + kc * 64 + g16);
    __syncthreads();   // A area now reusable for B buffers

    // ---- stage chunk 0 ----
    for (int t = tid; t < 1360; t += 256) gld16(packs + (size_t)t * 16, buf0 + (size_t)t * 16);
    __syncthreads();

    for (int c = 0; c < 14; ++c) {
        if (c + 1 < 14) {  // prefetch next chunk into other buffer
            const char* src = packs + (size_t)(c + 1) * GRU_BLOB;
            char* dstb = ((c + 1) & 1) ? buf1 : buf0;
            for (int t = tid; t < 1360; t += 256) gld16(src + (size_t)t * 16, dstb + (size_t)t * 16);
        }
        const char* buf = (c & 1) ? buf1 : buf0;

        f32x4 acc[4][3] = {};
        #pragma unroll
        for (int kc = 0; kc < 7; ++kc) {
            const bf16x8 b0 = *(const bf16x8*)(buf + (size_t)(0  + ln15) * 448 + kc * 64 + g16);
            const bf16x8 b1 = *(const bf16x8*)(buf + (size_t)(16 + ln15) * 448 + kc * 64 + g16);
            const bf16x8 b2 = *(const bf16x8*)(buf + (size_t)(32 + ln15) * 448 + kc * 64 + g16);
            #pragma unroll
            for (int Mt = 0; Mt < 4; ++Mt) {
                acc[Mt][0] = __builtin_amdgcn_mfma_f32_16x16x32_bf16(af[Mt][kc], b0, acc[Mt][0], 0, 0, 0);
                acc[Mt][1] = __builtin_amdgcn_mfma_f32_16x16x32_bf16(af[Mt][kc], b1, acc[Mt][1], 0, 0, 0);
                acc[Mt][2] = __builtin_amdgcn_mfma_f32_16x16x32_bf16(af[Mt][kc], b2, acc[Mt][2], 0, 0, 0);
            }
        }

        // ---- gate combine epilogue: acc[][0]=r, [1]=z, [2]=n pre-acts ----
        const float* bias = (const float*)(buf + 21504);
        const int dir = c / 7, cc = c - dir * 7;
        const int unit = cc * 16 + ln15;
        if (unit < NHW) {
            const float bR = bias[ln15], bZ = bias[16 + ln15];
            const float bN = bias[32 + ln15], hN = bias[48 + ln15];
            const int col = dir * NHW + unit;
            #pragma unroll
            for (int Mt = 0; Mt < 4; ++Mt)
                #pragma unroll
                for (int rg = 0; rg < 4; ++rg) {
                    const float r = fsig(acc[Mt][0][rg] + bR);
                    const float z = fsig(acc[Mt][1][rg] + bZ);
                    const float n = ftanh(acc[Mt][2][rg] + bN + r * hN);
                    const float h = (1.f - z) * n;
                    const long grow = rowbase + wv * 64 + Mt * 16 + (lane >> 4) * 4 + rg;
                    Hout[grow * 200 + col] = f2bf(h);
                }
        }
        __syncthreads();   // buf[c&1] free + prefetch complete
    }
}

// ============================ K3: attention + softmax + pool ===============
// Block: 4 groups (sentences/docs); wave w owns group blk*4+w, 64 padded rows.
// H rows staged to LDS (stay alive for pooling); scores via MFMA + tanh + ctx,
// reduced in-register; per-wave softmax; pooled bf16 row written to Out.
__global__ __launch_bounds__(256, 1) void attnpool_kernel(
    const unsigned short* __restrict__ Hin,  // [ngroups*nvalid][200] bf16
    const char* __restrict__ packs,          // 5 attn blobs
    const char* __restrict__ zp,
    const int nvalid,                        // 50 (words) or 40 (sentences)
    unsigned short* __restrict__ Out)        // [ngroups][200] bf16
{
    __shared__ __align__(16) char smem[114688 + 2 * 21888 + 2048];
    char* Ash  = smem;                                  // alive throughout
    char* buf0 = smem + 114688;
    char* buf1 = smem + 114688 + 21888;
    float* sc_sh = (float*)(smem + 114688 + 43776);     // [256]
    float* al_sh = sc_sh + 256;                         // [256]

    const int tid = threadIdx.x;
    const int lane = tid & 63, wv = tid >> 6;
    const int ln15 = lane & 15, g16 = (lane >> 4) * 16;

    // ---- stage H rows (64-padded per group) ----
    for (int t = tid; t < 7168; t += 256) {
        const int r = t / 28, u = t - r * 28;
        const int gl = r >> 6, item = r & 63;
        const char* src = zp;
        if (item < nvalid && u < 25) {
            const long grow = (long)(blockIdx.x * 4 + gl) * nvalid + item;
            src = (const char*)Hin + grow * 400 + (long)u * 16;
        }
        gld16(src, Ash + (size_t)t * 16);
    }
    __syncthreads();

    bf16x8 af[4][7];
    #pragma unroll
    for (int Mt = 0; Mt < 4; ++Mt)
        #pragma unroll
        for (int kc = 0; kc < 7; ++kc)
            af[Mt][kc] = *(const bf16x8*)(Ash + (size_t)(wv * 64 + Mt * 16 + ln15) * 448 + kc * 64 + g16);

    for (int t = tid; t < 1368; t += 256) gld16(packs + (size_t)t * 16, buf0 + (size_t)t * 16);
    __syncthreads();

    float sacc[4][4] = {{0.f}};   // [Mt][reg] score partials
    for (int c = 0; c < 5; ++c) {
        if (c + 1 < 5) {
            const char* src = packs + (size_t)(c + 1) * ATT_BLOB;
            char* dstb = ((c + 1) & 1) ? buf1 : buf0;
            for (int t = tid; t < 1368; t += 256) gld16(src + (size_t)t * 16, dstb + (size_t)t * 16);
        }
        const char* buf = (c & 1) ? buf1 : buf0;

        f32x4 acc[4][3] = {};
        #pragma unroll
        for (int kc = 0; kc < 7; ++kc) {
            const bf16x8 b0 = *(const bf16x8*)(buf + (size_t)(0  + ln15) * 448 + kc * 64 + g16);
            const bf16x8 b1 = *(const bf16x8*)(buf + (size_t)(16 + ln15) * 448 + kc * 64 + g16);
            const bf16x8 b2 = *(const bf16x8*)(buf + (size_t)(32 + ln15) * 448 + kc * 64 + g16);
            #pragma unroll
            for (int Mt = 0; Mt < 4; ++Mt) {
                acc[Mt][0] = __builtin_amdgcn_mfma_f32_16x16x32_bf16(af[Mt][kc], b0, acc[Mt][0], 0, 0, 0);
                acc[Mt][1] = __builtin_amdgcn_mfma_f32_16x16x32_bf16(af[Mt][kc], b1, acc[Mt][1], 0, 0, 0);
                acc[Mt][2] = __builtin_amdgcn_mfma_f32_16x16x32_bf16(af[Mt][kc], b2, acc[Mt][2], 0, 0, 0);
            }
        }
        const float* abp = (const float*)(buf + 21504);
        const float* cxp = (const float*)(buf + 21696);
        #pragma unroll
        for (int Nt = 0; Nt < 3; ++Nt) {
            const float ab = abp[Nt * 16 + ln15], cx = cxp[Nt * 16 + ln15];
            #pragma unroll
            for (int Mt = 0; Mt < 4; ++Mt)
                #pragma unroll
                for (int rg = 0; rg < 4; ++rg)
                    sacc[Mt][rg] += ftanh(acc[Mt][Nt][rg] + ab) * cx;
        }
        __syncthreads();
    }

    // ---- reduce scores across the 16 d-lanes, park per-row in LDS ----
    #pragma unroll
    for (int Mt = 0; Mt < 4; ++Mt)
        #pragma unroll
        for (int rg = 0; rg < 4; ++rg) {
            float v = sacc[Mt][rg];
            v += __shfl_xor(v, 1); v += __shfl_xor(v, 2);
            v += __shfl_xor(v, 4); v += __shfl_xor(v, 8);
            sacc[Mt][rg] = v;
        }
    if (ln15 == 0) {
        #pragma unroll
        for (int Mt = 0; Mt < 4; ++Mt)
            #pragma unroll
            for (int rg = 0; rg < 4; ++rg)
                sc_sh[wv * 64 + Mt * 16 + (lane >> 4) * 4 + rg] = sacc[Mt][rg];
    }

    // ---- per-wave softmax over 64 (masked to nvalid) ----
    const float s = (lane < nvalid) ? sc_sh[wv * 64 + lane] : -1e30f;
    float m = s;
    m = fmaxf(m, __shfl_xor(m, 1));  m = fmaxf(m, __shfl_xor(m, 2));
    m = fmaxf(m, __shfl_xor(m, 4));  m = fmaxf(m, __shfl_xor(m, 8));
    m = fmaxf(m, __shfl_xor(m, 16)); m = fmaxf(m, __shfl_xor(m, 32));
    const float e = (lane < nvalid) ? __expf(s - m) : 0.f;
    float ss = e;
    ss += __shfl_xor(ss, 1);  ss += __shfl_xor(ss, 2);
    ss += __shfl_xor(ss, 4);  ss += __shfl_xor(ss, 8);
    ss += __shfl_xor(ss, 16); ss += __shfl_xor(ss, 32);
    al_sh[wv * 64 + lane] = e * frcp(ss);

    // ---- pool: out[d] = sum_w alpha_w * H[w][d]  (H in Ash, pads are 0) ----
    const long orow = (long)blockIdx.x * 4 + wv;
    #pragma unroll
    for (int rnd = 0; rnd < 2; ++rnd) {
        const int d2 = rnd * 64 + lane;
        if (d2 < 100) {
            float fx = 0.f, fy = 0.f;
            #pragma unroll 8
            for (int w = 0; w < 64; ++w) {
                const float a = al_sh[wv * 64 + w];
                const unsigned int u = *(const unsigned int*)(Ash + (size_t)(wv * 64 + w) * 448 + d2 * 4);
                fx += a * bf2f_lo(u);
                fy += a * bf2f_hi(u);
            }
            const unsigned int o = (unsigned int)f2bf(fx) | ((unsigned int)f2bf(fy) << 16);
            ((unsigned int*)(Out + orow * 200))[d2] = o;
        }
    }
}

// ============================ K5: classifier + log_softmax =================
__global__ void cls_kernel(const unsigned short* __restrict__ dvec,
                           const float* __restrict__ fcW, const float* __restrict__ fcb,
                           float* __restrict__ out)
{
    const int doc = blockIdx.x, lane = threadIdx.x;  // 64 threads
    const int c = lane & 15, part = lane >> 4;
    const int cs = (c < NC) ? c : 0;
    float acc = (part == 0 && c < NC) ? fcb[c] : 0.f;
    for (int i = 0; i < 50; ++i) {
        const int k = part * 50 + i;
        const float a = bf2f_lo((unsigned int)dvec[(size_t)doc * 200 + k]);
        acc += a * ((c < NC) ? fcW[(size_t)cs * 200 + k] : 0.f);
    }
    acc += __shfl_xor(acc, 16); acc += __shfl_xor(acc, 32);
    const float lg = (c < NC) ? acc : -1e30f;
    float m = lg;
    m = fmaxf(m, __shfl_xor(m, 1)); m = fmaxf(m, __shfl_xor(m, 2));
    m = fmaxf(m, __shfl_xor(m, 4)); m = fmaxf(m, __shfl_xor(m, 8));
    const float e = (c < NC) ? __expf(lg - m) : 0.f;
    float ss = e;
    ss += __shfl_xor(ss, 1); ss += __shfl_xor(ss, 2);
    ss += __shfl_xor(ss, 4); ss += __shfl_xor(ss, 8);
    const float lse = m + __logf(ss);
    if (lane < NC) out[(size_t)doc * NC + lane] = lg - lse;
}

// ======================================================================
// Fallback fp32 path (round-1 kernels) — used only if ws_size < WS_NEED.
// ======================================================================
template<int NWRD, int WT>
__device__ __forceinline__ void encode_block(
    float* __restrict__ e_sh, float* __restrict__ h_sh, float* __restrict__ sc_sh,
    const float* __restrict__ Wf, const float* __restrict__ bihf, const float* __restrict__ bhhf,
    const float* __restrict__ Wb, const float* __restrict__ bihb, const float* __restrict__ bhhb,
    const float* __restrict__ aW, const float* __restrict__ ab, const float* __restrict__ actx,
    int tid)
{
    constexpr int WG = NWRD / WT;
    for (int item = tid; item < FEAT * WG; item += 256) {
        const int unit = item % FEAT, wg = item / FEAT;
        const int dir = unit / NHW, j = unit - dir * NHW;
        const float* Wd  = dir ? Wb : Wf;
        const float* bih = dir ? bihb : bihf;
        const float* bhh = dir ? bhhb : bhhf;
        const float4* rowR = (const float4*)(Wd + (size_t)j * ED);
        const float4* rowZ = (const float4*)(Wd + (size_t)(NHW + j) * ED);
        const float4* rowN = (const float4*)(Wd + (size_t)(2 * NHW + j) * ED);
        float aR[WT], aZ[WT], aN[WT];
        #pragma unroll
        for (int t = 0; t < WT; ++t) { aR[t] = 0.f; aZ[t] = 0.f; aN[t] = 0.f; }
        const int w0 = wg * WT;
        #pragma unroll 1
        for (int k4 = 0; k4 < ED / 4; ++k4) {
            const float4 wr = rowR[k4], wz = rowZ[k4], wn = rowN[k4];
            #pragma unroll
            for (int t = 0; t < WT; ++t) {
                const float4 e = *(const float4*)(e_sh + (w0 + t) * ED + k4 * 4);
                aR[t] += wr.x*e.x + wr.y*e.y + wr.z*e.z + wr.w*e.w;
                aZ[t] += wz.x*e.x + wz.y*e.y + wz.z*e.z + wz.w*e.w;
                aN[t] += wn.x*e.x + wn.y*e.y + wn.z*e.z + wn.w*e.w;
            }
        }
        const float bR = bih[j] + bhh[j], bZ = bih[NHW+j] + bhh[NHW+j];
        const float bN = bih[2*NHW+j], hN = bhh[2*NHW+j];
        #pragma unroll
        for (int t = 0; t < WT; ++t) {
            const float r = fsig(aR[t] + bR), z = fsig(aZ[t] + bZ);
            const float n = ftanh(aN[t] + bN + r * hN);
            h_sh[(w0 + t) * FEAT + unit] = (1.f - z) * n;
        }
    }
    __syncthreads();
    for (int item = tid; item < FEAT * WG; item += 256) {
        const int d = item % FEAT, wg = item / FEAT;
        const float4* row = (const float4*)(aW + (size_t)d * FEAT);
        float acc[WT];
        #pragma unroll
        for (int t = 0; t < WT; ++t) acc[t] = 0.f;
        const int w0 = wg * WT;
        #pragma unroll 1
        for (int k4 = 0; k4 < FEAT / 4; ++k4) {
            const float4 wv = row[k4];
            #pragma unroll
            for (int t = 0; t < WT; ++t) {
                const float4 h = *(const float4*)(h_sh + (w0 + t) * FEAT + k4 * 4);
                acc[t] += wv.x*h.x + wv.y*h.y + wv.z*h.z + wv.w*h.w;
            }
        }
        const float bb = ab[d], cc = actx[d];
        #pragma unroll
        for (int t = 0; t < WT; ++t)
            e_sh[d * NWRD + (w0 + t)] = ftanh(acc[t] + bb) * cc;
    }
    __syncthreads();
    if (tid < NWRD) {
        float s = 0.f;
        for (int d = 0; d < FEAT; ++d) s += e_sh[d * NWRD + tid];
        sc_sh[tid] = s;
    }
    __syncthreads();
    if (tid == 0) {
        float m = -1e30f;
        for (int w = 0; w < NWRD; ++w) m = fmaxf(m, sc_sh[w]);
        float s = 0.f;
        for (int w = 0; w < NWRD; ++w) { const float ev = __expf(sc_sh[w] - m); sc_sh[w] = ev; s += ev; }
        const float inv = 1.f / s;
        for (int w = 0; w < NWRD; ++w) sc_sh[w] *= inv;
    }
    __syncthreads();
}

__global__ __launch_bounds__(256) void word_kernel_f32(
    const int* __restrict__ x, const float* __restrict__ emb,
    const float* __restrict__ Wf, const float* __restrict__ bihf, const float* __restrict__ bhhf,
    const float* __restrict__ Wb, const float* __restrict__ bihb, const float* __restrict__ bhhb,
    const float* __restrict__ waW, const float* __restrict__ wab, const float* __restrict__ wactx,
    float* __restrict__ svec)
{
    __shared__ __align__(16) float e_sh[NW * ED];
    __shared__ __align__(16) float h_sh[NW * FEAT];
    __shared__ float sc_sh[NW];
    const int sent = blockIdx.x, tid = threadIdx.x;
    const int* xr = x + (size_t)sent * NW;
    for (int i = tid * 4; i < NW * ED; i += 256 * 4) {
        const int w = i / ED, k = i - w * ED;
        *(float4*)(e_sh + i) = *(const float4*)(emb + (size_t)xr[w] * ED + k);
    }
    __syncthreads();
    encode_block<NW, 25>(e_sh, h_sh, sc_sh, Wf, bihf, bhhf, Wb, bihb, bhhb, waW, wab, wactx, tid);
    if (tid < FEAT) {
        float a = 0.f;
        #pragma unroll 1
        for (int w = 0; w < NW; ++w) a += sc_sh[w] * h_sh[w * FEAT + tid];
        svec[(size_t)sent * FEAT + tid] = a;
    }
}

__global__ __launch_bounds__(256) void sent_kernel_f32(
    const float* __restrict__ svec,
    const float* __restrict__ Wf, const float* __restrict__ bihf, const float* __restrict__ bhhf,
    const float* __restrict__ Wb, const float* __restrict__ bihb, const float* __restrict__ bhhb,
    const float* __restrict__ saW, const float* __restrict__ sab, const float* __restrict__ sactx,
    const float* __restrict__ fcW, const float* __restrict__ fcb,
    float* __restrict__ out)
{
    __shared__ __align__(16) float e_sh[NS * ED];
    __shared__ __align__(16) float h_sh[NS * FEAT];
    __shared__ float sc_sh[NS];
    __shared__ float dvec_sh[FEAT];
    __shared__ float logit_sh[NC];
    __shared__ float lse_sh;
    const int b = blockIdx.x, tid = threadIdx.x;
    const float* src = svec + (size_t)b * NS * FEAT;
    for (int i = tid * 4; i < NS * FEAT; i += 256 * 4)
        *(float4*)(e_sh + i) = *(const float4*)(src + i);
    __syncthreads();
    encode_block<NS, 20>(e_sh, h_sh, sc_sh, Wf, bihf, bhhf, Wb, bihb, bhhb, saW, sab, sactx, tid);
    if (tid < FEAT) {
        float a = 0.f;
        #pragma unroll 1
        for (int s = 0; s < NS; ++s) a += sc_sh[s] * h_sh[s * FEAT + tid];
        dvec_sh[tid] = a;
    }
    __syncthreads();
    if (tid < NC) {
        float a = fcb[tid];
        const float* row = fcW + (size_t)tid * FEAT;
        for (int k = 0; k < FEAT; ++k) a += row[k] * dvec_sh[k];
        logit_sh[tid] = a;
    }
    __syncthreads();
    if (tid == 0) {
        float m = -1e30f;
        for (int c = 0; c < NC; ++c) m = fmaxf(m, logit_sh[c]);
        float s = 0.f;
        for (int c = 0; c < NC; ++c) s += __expf(logit_sh[c] - m);
        lse_sh = m + logf(s);
    }
    __syncthreads();
    if (tid < NC) out[(size_t)b * NC + tid] = logit_sh[tid] - lse_sh;
}

// ============================ launch =======================================
extern "C" void kernel_launch(void* const* d_in, const int* in_sizes, int n_in,
                              void* d_out, int out_size, void* d_ws, size_t ws_size,
                              hipStream_t stream)
{
    const int*   x     = (const int*)d_in[0];
    const float* emb   = (const float*)d_in[1];
    const float* wWf   = (const float*)d_in[2];
    const float* wbif  = (const float*)d_in[3];
    const float* wbhf  = (const float*)d_in[4];
    const float* wWb   = (const float*)d_in[5];
    const float* wbib  = (const float*)d_in[6];
    const float* wbhb  = (const float*)d_in[7];
    const float* waW   = (const float*)d_in[8];
    const float* wab   = (const float*)d_in[9];
    const float* wactx = (const float*)d_in[10];
    const float* sWf   = (const float*)d_in[11];
    const float* sbif  = (const float*)d_in[12];
    const float* sbhf  = (const float*)d_in[13];
    const float* sWb   = (const float*)d_in[14];
    const float* sbib  = (const float*)d_in[15];
    const float* sbhb  = (const float*)d_in[16];
    const float* saW   = (const float*)d_in[17];
    const float* sab   = (const float*)d_in[18];
    const float* sactx = (const float*)d_in[19];
    const float* fcW   = (const float*)d_in[20];
    const float* fcb   = (const float*)d_in[21];
    float* out = (float*)d_out;

    if (ws_size < WS_NEED) {
        // fallback fp32 path
        float* svec = (float*)d_ws;
        word_kernel_f32<<<NB * NS, 256, 0, stream>>>(
            x, emb, wWf, wbif, wbhf, wWb, wbib, wbhb, waW, wab, wactx, svec);
        sent_kernel_f32<<<NB, 256, 0, stream>>>(
            svec, sWf, sbif, sbhf, sWb, sbib, sbhb, saW, sab, sactx, fcW, fcb, out);
        return;
    }

    char* ws = (char*)d_ws;
    const char* zp = ws + OFF_ZPAD;

    pack_kernel<<<39, 256, 0, stream>>>(
        wWf, wbif, wbhf, wWb, wbib, wbhb, waW, wab, wactx,
        sWf, sbif, sbhf, sWb, sbib, sbhb, saW, sab, sactx, ws);
    embcvt_kernel<<<19532, 256, 0, stream>>>(emb, (unsigned short*)(ws + OFF_EMB));

    // word stage
    gru_kernel<true><<<MWORD / 256, 256, 0, stream>>>(
        x, ws + OFF_EMB, ws + OFF_PGW, zp, (unsigned short*)(ws + OFF_HW));
    attnpool_kernel<<<MSENT / 4, 256, 0, stream>>>(
        (const unsigned short*)(ws + OFF_HW), ws + OFF_PAW, zp, NW,
        (unsigned short*)(ws + OFF_SV));

    // sentence stage (same kernels, M = 5120)
    gru_kernel<false><<<MSENT / 256, 256, 0, stream>>>(
        nullptr, ws + OFF_SV, ws + OFF_PGS, zp, (unsigned short*)(ws + OFF_HS));
    attnpool_kernel<<<NB / 4, 256, 0, stream>>>(
        (const unsigned short*)(ws + OFF_HS), ws + OFF_PAS, zp, NS,
        (unsigned short*)(ws + OFF_DV));

    cls_kernel<<<NB, 64, 0, stream>>>(
        (const unsigned short*)(ws + OFF_DV), fcW, fcb, out);
}

// Round 3
// 457.561 us; speedup vs baseline: 7.0479x; 1.0297x over previous
//
#include <hip/hip_runtime.h>
#include <math.h>

// ============================ problem constants ============================
#define NB   128
#define NS   40
#define NW   50
#define ED   200   // = 2*HW = 2*HS
#define NHW  100
#define FEAT 200
#define NC   10
#define MWORD (NB*NS*NW)   // 256000 word rows
#define MSENT (NB*NS)      // 5120 sentence rows

// ============================ ws memory map (bytes) ========================
#define GRU_BLOB 21760ull            // 48*224*2 bf16 + 64 fp32 bias
#define ATT_BLOB 21888ull            // 48*224*2 bf16 + 48+48 fp32 (ab, ctx)
#define OFF_ZPAD 0ull
#define OFF_PGW  512ull
#define OFF_PAW  (OFF_PGW + 14ull*GRU_BLOB)     // 305,152
#define OFF_PGS  (OFF_PAW + 5ull*ATT_BLOB)      // 414,592
#define OFF_PAS  (OFF_PGS + 14ull*GRU_BLOB)     // 719,232
#define OFF_EMB  829440ull                      // emb bf16 [100000][200]
#define OFF_HW   (OFF_EMB + 40000000ull)        // H word [256000][200] bf16
#define OFF_SV   (OFF_HW + 102400000ull)        // svec [5120][200] bf16
#define OFF_HS   (OFF_SV + 2048000ull)          // H sent [5120][200] bf16
#define OFF_DV   (OFF_HS + 2048000ull)          // dvec [128][200] bf16
#define WS_NEED  (OFF_DV + 51200ull)            // 147,376,640 B

// LDS B-buffer: 48 rows x 29 16B-units (464 B stride; unit 28 = bias pad).
// 464 B = 116 dwords === 20 (mod 32), gcd(20,32)=4 -> ds_read_b128 frag reads
// spread uniformly over all 32 banks per 16-lane phase (2-deep = free).
#define BPAD 464
#define BUNITS (48*29)      // 1392 16B units
#define BBYTES (BUNITS*16)  // 22272

// ============================ helpers ======================================
typedef short bf16x8 __attribute__((ext_vector_type(8)));
typedef float f32x4  __attribute__((ext_vector_type(4)));

__device__ __forceinline__ unsigned short f2bf(float f) {
    unsigned int u = __float_as_uint(f);
    u += 0x7fffu + ((u >> 16) & 1u);          // RNE
    return (unsigned short)(u >> 16);
}
__device__ __forceinline__ float bf2f_lo(unsigned int u) { return __uint_as_float(u << 16); }
__device__ __forceinline__ float bf2f_hi(unsigned int u) { return __uint_as_float(u & 0xffff0000u); }
__device__ __forceinline__ float frcp(float x) { return __builtin_amdgcn_rcpf(x); }
__device__ __forceinline__ float fsig(float x) { return frcp(1.f + __expf(-x)); }
__device__ __forceinline__ float ftanh(float x){ return 1.f - 2.f*frcp(1.f + __expf(2.f*x)); }

// async global->LDS, 16B per lane. LDS dst is wave-uniform base + lane*16.
__device__ __forceinline__ void gld16(const void* g, void* l) {
    __builtin_amdgcn_global_load_lds(
        (const __attribute__((address_space(1))) void*)g,
        (__attribute__((address_space(3))) void*)l, 16, 0, 0);
}

// Stage one 48x448B blob into padded LDS (stride 464). Pad unit (u==28) of
// row r carries blob bias bytes [r*16, r*16+16) for r < biasRows, else zeros.
template<int NT>
__device__ __forceinline__ void stageB(char* __restrict__ dst,
                                       const char* __restrict__ blob,
                                       const char* __restrict__ zp,
                                       int tid, int biasRows)
{
    for (int t = tid; t < BUNITS; t += NT) {
        const int r = t / 29, u = t - r * 29;
        const char* src;
        if (u < 28)            src = blob + (size_t)r * 448 + (size_t)u * 16;
        else if (r < biasRows) src = blob + 21504 + (size_t)r * 16;
        else                   src = zp;
        gld16(src, dst + (size_t)t * 16);
    }
}

// ============================ P1: weight packing ===========================
// GRU blob: rows 0..15 = r-gate units [c*16..), 16..31 = z, 32..47 = n;
// cols 0..223 (K zero-padded); then 64 fp32: bR[16], bZ[16], bN[16], hN[16].
__global__ void pack_kernel(
    const float* __restrict__ wWf, const float* __restrict__ wbif, const float* __restrict__ wbhf,
    const float* __restrict__ wWb, const float* __restrict__ wbib, const float* __restrict__ wbhb,
    const float* __restrict__ waW, const float* __restrict__ wab, const float* __restrict__ wactx,
    const float* __restrict__ sWf, const float* __restrict__ sbif, const float* __restrict__ sbhf,
    const float* __restrict__ sWb, const float* __restrict__ sbib, const float* __restrict__ sbhb,
    const float* __restrict__ saW, const float* __restrict__ sab, const float* __restrict__ sactx,
    char* __restrict__ ws)
{
    const int b = blockIdx.x, tid = threadIdx.x;
    if (b == 38) { if (tid < 128) ((float*)(ws + OFF_ZPAD))[tid] = 0.f; return; }
    const bool word = b < 19;
    const int lb = word ? b : b - 19;
    if (lb < 14) {
        const int dir = lb / 7, c = lb % 7;
        const float* W   = word ? (dir ? wWb : wWf) : (dir ? sWb : sWf);
        const float* bih = word ? (dir ? wbib : wbif) : (dir ? sbib : sbif);
        const float* bhh = word ? (dir ? wbhb : wbhf) : (dir ? sbhb : sbhf);
        char* blob = ws + (word ? OFF_PGW : OFF_PGS) + (size_t)lb * GRU_BLOB;
        unsigned short* dst = (unsigned short*)blob;
        for (int e = tid; e < 48 * 224; e += 256) {
            const int row = e / 224, k = e - row * 224;
            const int g = row >> 4, j = c * 16 + (row & 15);
            const float v = (j < NHW && k < ED) ? W[(size_t)(g * NHW + j) * ED + k] : 0.f;
            dst[e] = f2bf(v);
        }
        if (tid < 64) {
            const int sect = tid >> 4, j = c * 16 + (tid & 15);
            float v = 0.f;
            if (j < NHW) {
                if (sect == 0)      v = bih[j] + bhh[j];
                else if (sect == 1) v = bih[NHW + j] + bhh[NHW + j];
                else if (sect == 2) v = bih[2 * NHW + j];
                else                v = bhh[2 * NHW + j];
            }
            ((float*)(blob + 21504))[tid] = v;
        }
    } else {
        const int c = lb - 14;
        const float* W  = word ? waW : saW;
        const float* ab = word ? wab : sab;
        const float* cx = word ? wactx : sactx;
        char* blob = ws + (word ? OFF_PAW : OFF_PAS) + (size_t)c * ATT_BLOB;
        unsigned short* dst = (unsigned short*)blob;
        for (int e = tid; e < 48 * 224; e += 256) {
            const int row = e / 224, k = e - row * 224;
            const int d = c * 48 + row;
            const float v = (d < FEAT && k < FEAT) ? W[(size_t)d * FEAT + k] : 0.f;
            dst[e] = f2bf(v);
        }
        if (tid < 48) {
            const int d = c * 48 + tid;
            ((float*)(blob + 21504))[tid] = (d < FEAT) ? ab[d] : 0.f;   // ab[48]
            ((float*)(blob + 21696))[tid] = (d < FEAT) ? cx[d] : 0.f;   // cx[48]
        }
    }
}

// ============================ P2: emb -> bf16 ==============================
__global__ void embcvt_kernel(const float* __restrict__ emb, unsigned short* __restrict__ dst)
{
    const long i = (long)blockIdx.x * 256 + threadIdx.x;   // float4 groups
    if (i < 5000000) {
        const float4 v = ((const float4*)emb)[i];
        ushort4 o;
        o.x = f2bf(v.x); o.y = f2bf(v.y); o.z = f2bf(v.z); o.w = f2bf(v.w);
        ((ushort4*)dst)[i] = o;
    }
}

// ============================ K2: bigru0 GEMM ==============================
// NWV waves; wave owns 64 rows (4 row-tiles). A-fragments loaded DIRECTLY
// from global into registers (no LDS staging, no bank conflicts); B blobs
// double-buffered in padded LDS via global_load_lds.
// MFMA operands SWAPPED: mfma(b_units, a_rows) -> lane holds D for
// unit = cc*16 + (lane>>4)*4 + rg, row = rowtile*16 + (lane&15):
// 4 consecutive units/lane -> dwordx2 stores, quad-aligned unit<100 mask.
template<bool GATHER, int NWV>
__global__ __launch_bounds__(64*NWV) void gru_kernel(
    const int* __restrict__ xtok,      // GATHER: token per row
    const char* __restrict__ abase,    // GATHER: emb_bf; else bf16 rows [.][400 B]
    const char* __restrict__ packs,    // 14 GRU blobs
    const char* __restrict__ zp,       // 512 B zeros
    unsigned short* __restrict__ Hout) // [M][200] bf16
{
    __shared__ __align__(16) char smem[2 * BBYTES];
    char* buf0 = smem;
    char* buf1 = smem + BBYTES;

    const int tid  = threadIdx.x;
    const int lane = tid & 63, wv = tid >> 6;
    const int ln15 = lane & 15, q = lane >> 4;
    const int g16  = q * 16;
    const long rowbase = (long)blockIdx.x * (64 * NWV);

    // ---- A fragments straight from global ----
    bf16x8 af[4][7];
    #pragma unroll
    for (int Mt = 0; Mt < 4; ++Mt) {
        const long ridx = rowbase + wv * 64 + Mt * 16 + ln15;
        const long rid  = GATHER ? (long)xtok[ridx] : ridx;
        const char* rp  = abase + rid * 400;
        #pragma unroll
        for (int kc = 0; kc < 7; ++kc) {
            if (kc * 64 + g16 < 400) af[Mt][kc] = *(const bf16x8*)(rp + kc * 64 + g16);
            else                     af[Mt][kc] = (bf16x8)(short)0;
        }
    }

    stageB<64*NWV>(buf0, packs, zp, tid, 16);
    __syncthreads();

    for (int c = 0; c < 14; ++c) {
        if (c + 1 < 14)
            stageB<64*NWV>(((c + 1) & 1) ? buf1 : buf0,
                           packs + (size_t)(c + 1) * GRU_BLOB, zp, tid, 16);
        const char* buf = (c & 1) ? buf1 : buf0;

        f32x4 acc[3][4] = {};   // [gate][rowtile]
        #pragma unroll
        for (int kc = 0; kc < 7; ++kc) {
            const bf16x8 b0 = *(const bf16x8*)(buf + (size_t)(0  + ln15) * BPAD + kc * 64 + g16);
            const bf16x8 b1 = *(const bf16x8*)(buf + (size_t)(16 + ln15) * BPAD + kc * 64 + g16);
            const bf16x8 b2 = *(const bf16x8*)(buf + (size_t)(32 + ln15) * BPAD + kc * 64 + g16);
            #pragma unroll
            for (int Mt = 0; Mt < 4; ++Mt) {
                acc[0][Mt] = __builtin_amdgcn_mfma_f32_16x16x32_bf16(b0, af[Mt][kc], acc[0][Mt], 0, 0, 0);
                acc[1][Mt] = __builtin_amdgcn_mfma_f32_16x16x32_bf16(b1, af[Mt][kc], acc[1][Mt], 0, 0, 0);
                acc[2][Mt] = __builtin_amdgcn_mfma_f32_16x16x32_bf16(b2, af[Mt][kc], acc[2][Mt], 0, 0, 0);
            }
        }

        // ---- gate combine epilogue ----
        const int dir = c / 7, cc = c - dir * 7;
        if (cc * 16 + q * 4 < NHW) {    // quad-aligned validity
            // bias float i (i = sect*16 + q*4 + rg) lives at LDS row
            // (4*sect + q), pad offset 448 + 4*rg -> one b128 per section.
            const f32x4 bR4 = *(const f32x4*)(buf + (size_t)(0  + q) * BPAD + 448);
            const f32x4 bZ4 = *(const f32x4*)(buf + (size_t)(4  + q) * BPAD + 448);
            const f32x4 bN4 = *(const f32x4*)(buf + (size_t)(8  + q) * BPAD + 448);
            const f32x4 hN4 = *(const f32x4*)(buf + (size_t)(12 + q) * BPAD + 448);
            const int ubase = dir * NHW + cc * 16 + q * 4;
            #pragma unroll
            for (int Mt = 0; Mt < 4; ++Mt) {
                unsigned int h01, h23;
                {
                    const float r0 = fsig(acc[0][Mt][0] + bR4[0]);
                    const float z0 = fsig(acc[1][Mt][0] + bZ4[0]);
                    const float n0 = ftanh(acc[2][Mt][0] + bN4[0] + r0 * hN4[0]);
                    const float r1 = fsig(acc[0][Mt][1] + bR4[1]);
                    const float z1 = fsig(acc[1][Mt][1] + bZ4[1]);
                    const float n1 = ftanh(acc[2][Mt][1] + bN4[1] + r1 * hN4[1]);
                    h01 = (unsigned int)f2bf((1.f - z0) * n0) | ((unsigned int)f2bf((1.f - z1) * n1) << 16);
                    const float r2 = fsig(acc[0][Mt][2] + bR4[2]);
                    const float z2 = fsig(acc[1][Mt][2] + bZ4[2]);
                    const float n2 = ftanh(acc[2][Mt][2] + bN4[2] + r2 * hN4[2]);
                    const float r3 = fsig(acc[0][Mt][3] + bR4[3]);
                    const float z3 = fsig(acc[1][Mt][3] + bZ4[3]);
                    const float n3 = ftanh(acc[2][Mt][3] + bN4[3] + r3 * hN4[3]);
                    h23 = (unsigned int)f2bf((1.f - z2) * n2) | ((unsigned int)f2bf((1.f - z3) * n3) << 16);
                }
                const long row = rowbase + wv * 64 + Mt * 16 + ln15;
                uint2 o; o.x = h01; o.y = h23;
                *(uint2*)(Hout + row * 200 + ubase) = o;
            }
        }
        __syncthreads();
    }
}

// ============================ K3: attention + softmax + pool ===============
// Block: 4 groups; wave = 1 group (64 padded rows). A-frags direct from
// global H (masked); B blobs in padded LDS (double-buffered). No H in LDS —
// pooling re-reads H rows from global (L2/L3-hot, coalesced dwordx2).
__global__ __launch_bounds__(256) void attnpool_kernel(
    const unsigned short* __restrict__ Hin,  // [ngroups*nvalid][200] bf16
    const char* __restrict__ packs,          // 5 attn blobs
    const char* __restrict__ zp,
    const int nvalid,                        // 50 (words) or 40 (sentences)
    unsigned short* __restrict__ Out)        // [ngroups][200] bf16
{
    __shared__ __align__(16) char smem[2 * BBYTES + 2048];
    char* buf0 = smem;
    char* buf1 = smem + BBYTES;
    float* sc_sh = (float*)(smem + 2 * BBYTES);   // [256]
    float* al_sh = sc_sh + 256;                   // [256]

    const int tid  = threadIdx.x;
    const int lane = tid & 63, wv = tid >> 6;
    const int ln15 = lane & 15, q = lane >> 4;
    const int g16  = q * 16;
    const long grp = (long)blockIdx.x * 4 + wv;
    const char* Hbase = (const char*)Hin + grp * nvalid * 400;

    // ---- A fragments from global H, masked to nvalid ----
    bf16x8 af[4][7];
    #pragma unroll
    for (int Mt = 0; Mt < 4; ++Mt) {
        const int item = Mt * 16 + ln15;
        const char* rp = Hbase + (long)item * 400;
        #pragma unroll
        for (int kc = 0; kc < 7; ++kc) {
            if (item < nvalid && kc * 64 + g16 < 400) af[Mt][kc] = *(const bf16x8*)(rp + kc * 64 + g16);
            else                                      af[Mt][kc] = (bf16x8)(short)0;
        }
    }

    stageB<256>(buf0, packs, zp, tid, 24);
    __syncthreads();

    float sacc[4][4] = {{0.f}};   // [Mt][reg] score partials (unswapped layout)
    for (int c = 0; c < 5; ++c) {
        if (c + 1 < 5)
            stageB<256>(((c + 1) & 1) ? buf1 : buf0,
                        packs + (size_t)(c + 1) * ATT_BLOB, zp, tid, 24);
        const char* buf = (c & 1) ? buf1 : buf0;

        f32x4 acc[4][3] = {};
        #pragma unroll
        for (int kc = 0; kc < 7; ++kc) {
            const bf16x8 b0 = *(const bf16x8*)(buf + (size_t)(0  + ln15) * BPAD + kc * 64 + g16);
            const bf16x8 b1 = *(const bf16x8*)(buf + (size_t)(16 + ln15) * BPAD + kc * 64 + g16);
            const bf16x8 b2 = *(const bf16x8*)(buf + (size_t)(32 + ln15) * BPAD + kc * 64 + g16);
            #pragma unroll
            for (int Mt = 0; Mt < 4; ++Mt) {
                acc[Mt][0] = __builtin_amdgcn_mfma_f32_16x16x32_bf16(af[Mt][kc], b0, acc[Mt][0], 0, 0, 0);
                acc[Mt][1] = __builtin_amdgcn_mfma_f32_16x16x32_bf16(af[Mt][kc], b1, acc[Mt][1], 0, 0, 0);
                acc[Mt][2] = __builtin_amdgcn_mfma_f32_16x16x32_bf16(af[Mt][kc], b2, acc[Mt][2], 0, 0, 0);
            }
        }
        // ab[d], cx[d], d = c*48 + Nt*16 + ln15; bias byte b -> LDS row b>>4,
        // pad offset 448 + (b&15). ab at blob+21504 (byte 0), cx at +21696 (192).
        #pragma unroll
        for (int Nt = 0; Nt < 3; ++Nt) {
            const int bo = 4 * (Nt * 16 + ln15);
            const float ab = *(const float*)(buf + (size_t)(bo >> 4) * BPAD + 448 + (bo & 15));
            const int co = 192 + bo;
            const float cx = *(const float*)(buf + (size_t)(co >> 4) * BPAD + 448 + (co & 15));
            #pragma unroll
            for (int Mt = 0; Mt < 4; ++Mt)
                #pragma unroll
                for (int rg = 0; rg < 4; ++rg)
                    sacc[Mt][rg] += ftanh(acc[Mt][Nt][rg] + ab) * cx;
        }
        __syncthreads();
    }

    // ---- reduce scores across the 16 d-lanes, park per-row in LDS ----
    #pragma unroll
    for (int Mt = 0; Mt < 4; ++Mt)
        #pragma unroll
        for (int rg = 0; rg < 4; ++rg) {
            float v = sacc[Mt][rg];
            v += __shfl_xor(v, 1); v += __shfl_xor(v, 2);
            v += __shfl_xor(v, 4); v += __shfl_xor(v, 8);
            sacc[Mt][rg] = v;
        }
    if (ln15 == 0) {
        #pragma unroll
        for (int Mt = 0; Mt < 4; ++Mt)
            #pragma unroll
            for (int rg = 0; rg < 4; ++rg)
                sc_sh[wv * 64 + Mt * 16 + q * 4 + rg] = sacc[Mt][rg];
    }
    __syncthreads();

    // ---- per-wave softmax over 64 (masked to nvalid) ----
    const float s = (lane < nvalid) ? sc_sh[wv * 64 + lane] : -1e30f;
    float m = s;
    m = fmaxf(m, __shfl_xor(m, 1));  m = fmaxf(m, __shfl_xor(m, 2));
    m = fmaxf(m, __shfl_xor(m, 4));  m = fmaxf(m, __shfl_xor(m, 8));
    m = fmaxf(m, __shfl_xor(m, 16)); m = fmaxf(m, __shfl_xor(m, 32));
    const float e = (lane < nvalid) ? __expf(s - m) : 0.f;
    float ss = e;
    ss += __shfl_xor(ss, 1);  ss += __shfl_xor(ss, 2);
    ss += __shfl_xor(ss, 4);  ss += __shfl_xor(ss, 8);
    ss += __shfl_xor(ss, 16); ss += __shfl_xor(ss, 32);
    al_sh[wv * 64 + lane] = e * frcp(ss);
    __syncthreads();

    // ---- pool from GLOBAL H: lane covers one 8B chunk (4 bf16) ----
    if (lane < 50) {
        float a0 = 0.f, a1 = 0.f, a2 = 0.f, a3 = 0.f;
        #pragma unroll 5
        for (int w = 0; w < nvalid; ++w) {
            const float a = al_sh[wv * 64 + w];
            const uint2 u = *(const uint2*)(Hbase + (long)w * 400 + lane * 8);
            a0 += a * bf2f_lo(u.x); a1 += a * bf2f_hi(u.x);
            a2 += a * bf2f_lo(u.y); a3 += a * bf2f_hi(u.y);
        }
        uint2 o;
        o.x = (unsigned int)f2bf(a0) | ((unsigned int)f2bf(a1) << 16);
        o.y = (unsigned int)f2bf(a2) | ((unsigned int)f2bf(a3) << 16);
        *(uint2*)((char*)(Out + grp * 200) + lane * 8) = o;
    }
}

// ============================ K5: classifier + log_softmax =================
__global__ void cls_kernel(const unsigned short* __restrict__ dvec,
                           const float* __restrict__ fcW, const float* __restrict__ fcb,
                           float* __restrict__ out)
{
    const int doc = blockIdx.x, lane = threadIdx.x;  // 64 threads
    const int c = lane & 15, part = lane >> 4;
    const int cs = (c < NC) ? c : 0;
    float acc = (part == 0 && c < NC) ? fcb[c] : 0.f;
    for (int i = 0; i < 50; ++i) {
        const int k = part * 50 + i;
        const float a = bf2f_lo((unsigned int)dvec[(size_t)doc * 200 + k]);
        acc += a * ((c < NC) ? fcW[(size_t)cs * 200 + k] : 0.f);
    }
    acc += __shfl_xor(acc, 16); acc += __shfl_xor(acc, 32);
    const float lg = (c < NC) ? acc : -1e30f;
    float m = lg;
    m = fmaxf(m, __shfl_xor(m, 1)); m = fmaxf(m, __shfl_xor(m, 2));
    m = fmaxf(m, __shfl_xor(m, 4)); m = fmaxf(m, __shfl_xor(m, 8));
    const float e = (c < NC) ? __expf(lg - m) : 0.f;
    float ss = e;
    ss += __shfl_xor(ss, 1); ss += __shfl_xor(ss, 2);
    ss += __shfl_xor(ss, 4); ss += __shfl_xor(ss, 8);
    const float lse = m + __logf(ss);
    if (lane < NC) out[(size_t)doc * NC + lane] = lg - lse;
}

// ======================================================================
// Fallback fp32 path — used only if ws_size < WS_NEED.
// ======================================================================
template<int NWRD, int WT>
__device__ __forceinline__ void encode_block(
    float* __restrict__ e_sh, float* __restrict__ h_sh, float* __restrict__ sc_sh,
    const float* __restrict__ Wf, const float* __restrict__ bihf, const float* __restrict__ bhhf,
    const float* __restrict__ Wb, const float* __restrict__ bihb, const float* __restrict__ bhhb,
    const float* __restrict__ aW, const float* __restrict__ ab, const float* __restrict__ actx,
    int tid)
{
    constexpr int WG = NWRD / WT;
    for (int item = tid; item < FEAT * WG; item += 256) {
        const int unit = item % FEAT, wg = item / FEAT;
        const int dir = unit / NHW, j = unit - dir * NHW;
        const float* Wd  = dir ? Wb : Wf;
        const float* bih = dir ? bihb : bihf;
        const float* bhh = dir ? bhhb : bhhf;
        const float4* rowR = (const float4*)(Wd + (size_t)j * ED);
        const float4* rowZ = (const float4*)(Wd + (size_t)(NHW + j) * ED);
        const float4* rowN = (const float4*)(Wd + (size_t)(2 * NHW + j) * ED);
        float aR[WT], aZ[WT], aN[WT];
        #pragma unroll
        for (int t = 0; t < WT; ++t) { aR[t] = 0.f; aZ[t] = 0.f; aN[t] = 0.f; }
        const int w0 = wg * WT;
        #pragma unroll 1
        for (int k4 = 0; k4 < ED / 4; ++k4) {
            const float4 wr = rowR[k4], wz = rowZ[k4], wn = rowN[k4];
            #pragma unroll
            for (int t = 0; t < WT; ++t) {
                const float4 e = *(const float4*)(e_sh + (w0 + t) * ED + k4 * 4);
                aR[t] += wr.x*e.x + wr.y*e.y + wr.z*e.z + wr.w*e.w;
                aZ[t] += wz.x*e.x + wz.y*e.y + wz.z*e.z + wz.w*e.w;
                aN[t] += wn.x*e.x + wn.y*e.y + wn.z*e.z + wn.w*e.w;
            }
        }
        const float bR = bih[j] + bhh[j], bZ = bih[NHW+j] + bhh[NHW+j];
        const float bN = bih[2*NHW+j], hN = bhh[2*NHW+j];
        #pragma unroll
        for (int t = 0; t < WT; ++t) {
            const float r = fsig(aR[t] + bR), z = fsig(aZ[t] + bZ);
            const float n = ftanh(aN[t] + bN + r * hN);
            h_sh[(w0 + t) * FEAT + unit] = (1.f - z) * n;
        }
    }
    __syncthreads();
    for (int item = tid; item < FEAT * WG; item += 256) {
        const int d = item % FEAT, wg = item / FEAT;
        const float4* row = (const float4*)(aW + (size_t)d * FEAT);
        float acc[WT];
        #pragma unroll
        for (int t = 0; t < WT; ++t) acc[t] = 0.f;
        const int w0 = wg * WT;
        #pragma unroll 1
        for (int k4 = 0; k4 < FEAT / 4; ++k4) {
            const float4 wv = row[k4];
            #pragma unroll
            for (int t = 0; t < WT; ++t) {
                const float4 h = *(const float4*)(h_sh + (w0 + t) * FEAT + k4 * 4);
                acc[t] += wv.x*h.x + wv.y*h.y + wv.z*h.z + wv.w*h.w;
            }
        }
        const float bb = ab[d], cc = actx[d];
        #pragma unroll
        for (int t = 0; t < WT; ++t)
            e_sh[d * NWRD + (w0 + t)] = ftanh(acc[t] + bb) * cc;
    }
    __syncthreads();
    if (tid < NWRD) {
        float s = 0.f;
        for (int d = 0; d < FEAT; ++d) s += e_sh[d * NWRD + tid];
        sc_sh[tid] = s;
    }
    __syncthreads();
    if (tid == 0) {
        float m = -1e30f;
        for (int w = 0; w < NWRD; ++w) m = fmaxf(m, sc_sh[w]);
        float s = 0.f;
        for (int w = 0; w < NWRD; ++w) { const float ev = __expf(sc_sh[w] - m); sc_sh[w] = ev; s += ev; }
        const float inv = 1.f / s;
        for (int w = 0; w < NWRD; ++w) sc_sh[w] *= inv;
    }
    __syncthreads();
}

__global__ __launch_bounds__(256) void word_kernel_f32(
    const int* __restrict__ x, const float* __restrict__ emb,
    const float* __restrict__ Wf, const float* __restrict__ bihf, const float* __restrict__ bhhf,
    const float* __restrict__ Wb, const float* __restrict__ bihb, const float* __restrict__ bhhb,
    const float* __restrict__ waW, const float* __restrict__ wab, const float* __restrict__ wactx,
    float* __restrict__ svec)
{
    __shared__ __align__(16) float e_sh[NW * ED];
    __shared__ __align__(16) float h_sh[NW * FEAT];
    __shared__ float sc_sh[NW];
    const int sent = blockIdx.x, tid = threadIdx.x;
    const int* xr = x + (size_t)sent * NW;
    for (int i = tid * 4; i < NW * ED; i += 256 * 4) {
        const int w = i / ED, k = i - w * ED;
        *(float4*)(e_sh + i) = *(const float4*)(emb + (size_t)xr[w] * ED + k);
    }
    __syncthreads();
    encode_block<NW, 25>(e_sh, h_sh, sc_sh, Wf, bihf, bhhf, Wb, bihb, bhhb, waW, wab, wactx, tid);
    if (tid < FEAT) {
        float a = 0.f;
        #pragma unroll 1
        for (int w = 0; w < NW; ++w) a += sc_sh[w] * h_sh[w * FEAT + tid];
        svec[(size_t)sent * FEAT + tid] = a;
    }
}

__global__ __launch_bounds__(256) void sent_kernel_f32(
    const float* __restrict__ svec,
    const float* __restrict__ Wf, const float* __restrict__ bihf, const float* __restrict__ bhhf,
    const float* __restrict__ Wb, const float* __restrict__ bihb, const float* __restrict__ bhhb,
    const float* __restrict__ saW, const float* __restrict__ sab, const float* __restrict__ sactx,
    const float* __restrict__ fcW, const float* __restrict__ fcb,
    float* __restrict__ out)
{
    __shared__ __align__(16) float e_sh[NS * ED];
    __shared__ __align__(16) float h_sh[NS * FEAT];
    __shared__ float sc_sh[NS];
    __shared__ float dvec_sh[FEAT];
    __shared__ float logit_sh[NC];
    __shared__ float lse_sh;
    const int b = blockIdx.x, tid = threadIdx.x;
    const float* src = svec + (size_t)b * NS * FEAT;
    for (int i = tid * 4; i < NS * FEAT; i += 256 * 4)
        *(float4*)(e_sh + i) = *(const float4*)(src + i);
    __syncthreads();
    encode_block<NS, 20>(e_sh, h_sh, sc_sh, Wf, bihf, bhhf, Wb, bihb, bhhb, saW, sab, sactx, tid);
    if (tid < FEAT) {
        float a = 0.f;
        #pragma unroll 1
        for (int s = 0; s < NS; ++s) a += sc_sh[s] * h_sh[s * FEAT + tid];
        dvec_sh[tid] = a;
    }
    __syncthreads();
    if (tid < NC) {
        float a = fcb[tid];
        const float* row = fcW + (size_t)tid * FEAT;
        for (int k = 0; k < FEAT; ++k) a += row[k] * dvec_sh[k];
        logit_sh[tid] = a;
    }
    __syncthreads();
    if (tid == 0) {
        float m = -1e30f;
        for (int c = 0; c < NC; ++c) m = fmaxf(m, logit_sh[c]);
        float s = 0.f;
        for (int c = 0; c < NC; ++c) s += __expf(logit_sh[c] - m);
        lse_sh = m + logf(s);
    }
    __syncthreads();
    if (tid < NC) out[(size_t)b * NC + tid] = logit_sh[tid] - lse_sh;
}

// ============================ launch =======================================
extern "C" void kernel_launch(void* const* d_in, const int* in_sizes, int n_in,
                              void* d_out, int out_size, void* d_ws, size_t ws_size,
                              hipStream_t stream)
{
    const int*   x     = (const int*)d_in[0];
    const float* emb   = (const float*)d_in[1];
    const float* wWf   = (const float*)d_in[2];
    const float* wbif  = (const float*)d_in[3];
    const float* wbhf  = (const float*)d_in[4];
    const float* wWb   = (const float*)d_in[5];
    const float* wbib  = (const float*)d_in[6];
    const float* wbhb  = (const float*)d_in[7];
    const float* waW   = (const float*)d_in[8];
    const float* wab   = (const float*)d_in[9];
    const float* wactx = (const float*)d_in[10];
    const float* sWf   = (const float*)d_in[11];
    const float* sbif  = (const float*)d_in[12];
    const float* sbhf  = (const float*)d_in[13];
    const float* sWb   = (const float*)d_in[14];
    const float* sbib  = (const float*)d_in[15];
    const float* sbhb  = (const float*)d_in[16];
    const float* saW   = (const float*)d_in[17];
    const float* sab   = (const float*)d_in[18];
    const float* sactx = (const float*)d_in[19];
    const float* fcW   = (const float*)d_in[20];
    const float* fcb   = (const float*)d_in[21];
    float* out = (float*)d_out;

    if (ws_size < WS_NEED) {
        float* svec = (float*)d_ws;
        word_kernel_f32<<<NB * NS, 256, 0, stream>>>(
            x, emb, wWf, wbif, wbhf, wWb, wbib, wbhb, waW, wab, wactx, svec);
        sent_kernel_f32<<<NB, 256, 0, stream>>>(
            svec, sWf, sbif, sbhf, sWb, sbib, sbhb, saW, sab, sactx, fcW, fcb, out);
        return;
    }

    char* ws = (char*)d_ws;
    const char* zp = ws + OFF_ZPAD;

    pack_kernel<<<39, 256, 0, stream>>>(
        wWf, wbif, wbhf, wWb, wbib, wbhb, waW, wab, wactx,
        sWf, sbif, sbhf, sWb, sbib, sbhb, saW, sab, sactx, ws);
    embcvt_kernel<<<19532, 256, 0, stream>>>(emb, (unsigned short*)(ws + OFF_EMB));

    // word stage
    gru_kernel<true, 4><<<MWORD / 256, 256, 0, stream>>>(
        x, ws + OFF_EMB, ws + OFF_PGW, zp, (unsigned short*)(ws + OFF_HW));
    attnpool_kernel<<<MSENT / 4, 256, 0, stream>>>(
        (const unsigned short*)(ws + OFF_HW), ws + OFF_PAW, zp, NW,
        (unsigned short*)(ws + OFF_SV));

    // sentence stage (64-row blocks -> 80 blocks for better CU coverage)
    gru_kernel<false, 1><<<MSENT / 64, 64, 0, stream>>>(
        nullptr, ws + OFF_SV, ws + OFF_PGS, zp, (unsigned short*)(ws + OFF_HS));
    attnpool_kernel<<<NB / 4, 256, 0, stream>>>(
        (const unsigned short*)(ws + OFF_HS), ws + OFF_PAS, zp, NS,
        (unsigned short*)(ws + OFF_DV));

    cls_kernel<<<NB, 64, 0, stream>>>(
        (const unsigned short*)(ws + OFF_DV), fcW, fcb, out);
}

// Round 4
// 432.410 us; speedup vs baseline: 7.4579x; 1.0582x over previous
//
#include <hip/hip_runtime.h>
#include <math.h>

// ============================ problem constants ============================
#define NB    128
#define NS    40
#define NW    50
#define ED    200   // = 2*HW = 2*HS
#define NHW   100
#define FEAT  200
#define NC    10
#define VOCABM1 99999
#define KL2E  1.4426950408889634f

// ============================ ws memory map (bytes) ========================
// All weight blobs pre-padded: 48 rows x 464 B (28x16B bf16 weights, K padded
// to 224 with zeros, + 16 B pad unit carrying fp32 bias/ctx constants).
#define BB       22272ull
#define OFF_PGW  0ull
#define OFF_PAW  (14ull*BB)            // 311,808
#define OFF_PGS  (OFF_PAW + 5ull*BB)   // 423,168
#define OFF_PAS  (OFF_PGS + 14ull*BB)  // 734,976
#define OFF_SV   846336ull             // svec [5120][200] bf16 = 2,048,000
#define OFF_DV   2894336ull            // dvec [128][200] bf16 = 51,200
#define WS_NEED  4194304ull            // covers fp32 fallback's svec too

// ============================ helpers ======================================
typedef short bf16x8 __attribute__((ext_vector_type(8)));
typedef float f32x4  __attribute__((ext_vector_type(4)));

__device__ __forceinline__ unsigned short f2bf(float f) {
    unsigned int u = __float_as_uint(f);
    u += 0x7fffu + ((u >> 16) & 1u);          // RNE
    return (unsigned short)(u >> 16);
}
__device__ __forceinline__ float bf2f(short s) {
    return __uint_as_float(((unsigned int)(unsigned short)s) << 16);
}
__device__ __forceinline__ float frcp(float x) { return __builtin_amdgcn_rcpf(x); }
#if __has_builtin(__builtin_amdgcn_exp2f)
__device__ __forceinline__ float fexp2(float x){ return __builtin_amdgcn_exp2f(x); }
#else
__device__ __forceinline__ float fexp2(float x){ return exp2f(x); }
#endif
__device__ __forceinline__ float fsig(float x) { return frcp(1.f + __expf(-x)); }
__device__ __forceinline__ float ftanh(float x){ return 1.f - 2.f*frcp(1.f + __expf(2.f*x)); }
__device__ __forceinline__ unsigned pk2(float a, float b) {
    return (unsigned)f2bf(a) | ((unsigned)f2bf(b) << 16);
}

// async global->LDS, 16B per lane; LDS dst = wave-uniform base + lane*16.
__device__ __forceinline__ void gld16(const void* g, void* l) {
    __builtin_amdgcn_global_load_lds(
        (const __attribute__((address_space(1))) void*)g,
        (__attribute__((address_space(3))) void*)l, 16, 0, 0);
}

// linear blob stage: 1392 16B units, 512 threads
__device__ __forceinline__ void stageBlob(char* __restrict__ dst,
                                          const char* __restrict__ src, int tid)
{
    gld16(src + (size_t)tid * 16,          dst + (size_t)tid * 16);
    gld16(src + (size_t)(512 + tid) * 16,  dst + (size_t)(512 + tid) * 16);
    if (tid < 368)
        gld16(src + (size_t)(1024 + tid) * 16, dst + (size_t)(1024 + tid) * 16);
}

__device__ __forceinline__ bf16x8 pack8(float4 a, float4 b) {
    bf16x8 r;
    r[0]=(short)f2bf(a.x); r[1]=(short)f2bf(a.y); r[2]=(short)f2bf(a.z); r[3]=(short)f2bf(a.w);
    r[4]=(short)f2bf(b.x); r[5]=(short)f2bf(b.y); r[6]=(short)f2bf(b.z); r[7]=(short)f2bf(b.w);
    return r;
}

// ============================ P1: weight packing ===========================
// 38 blocks: 0..13 word GRU (dir*7+c), 14..18 word attn, 19..32 sent GRU,
// 33..37 sent attn. GRU pad rows 0..15: [bR'(16) bZ'(16) bN2(16) hN2(16)],
// bR' = -K(bihR+bhhR), bZ' = K(bihZ+bhhZ), bN2 = 2K*bihN, hN2 = 2K*bhhN.
// Attn pad rows 0..11: ab2 = 2K*ab; rows 12..23: cx2n = -2*cx.
__global__ void pack_kernel(
    const float* __restrict__ wWf, const float* __restrict__ wbif, const float* __restrict__ wbhf,
    const float* __restrict__ wWb, const float* __restrict__ wbib, const float* __restrict__ wbhb,
    const float* __restrict__ waW, const float* __restrict__ wab, const float* __restrict__ wactx,
    const float* __restrict__ sWf, const float* __restrict__ sbif, const float* __restrict__ sbhf,
    const float* __restrict__ sWb, const float* __restrict__ sbib, const float* __restrict__ sbhb,
    const float* __restrict__ saW, const float* __restrict__ sab, const float* __restrict__ sactx,
    char* __restrict__ ws)
{
    const int b = blockIdx.x, tid = threadIdx.x;
    const bool word = b < 19;
    const int lb = word ? b : b - 19;
    char* blob;
    if (lb < 14) blob = ws + (word ? OFF_PGW : OFF_PGS) + (size_t)lb * BB;
    else         blob = ws + (word ? OFF_PAW : OFF_PAS) + (size_t)(lb - 14) * BB;

    for (int i = tid; i < (int)(BB / 4); i += 256) ((unsigned*)blob)[i] = 0u;
    __syncthreads();

    unsigned short* w16 = (unsigned short*)blob;
    if (lb < 14) {
        const int dir = lb / 7, c = lb % 7;
        const float* W   = word ? (dir ? wWb : wWf) : (dir ? sWb : sWf);
        const float* bih = word ? (dir ? wbib : wbif) : (dir ? sbib : sbif);
        const float* bhh = word ? (dir ? wbhb : wbhf) : (dir ? sbhb : sbhf);
        for (int e = tid; e < 48 * 200; e += 256) {
            const int row = e / 200, k = e - row * 200;
            const int gate = row >> 4, j = c * 16 + (row & 15);
            if (j < NHW) w16[row * 232 + k] = f2bf(W[(size_t)(gate * NHW + j) * ED + k]);
        }
        if (tid < 64) {
            const int sect = tid >> 4, j = c * 16 + (tid & 15);
            float v = 0.f;
            if (j < NHW) {
                if (sect == 0)      v = -KL2E * (bih[j] + bhh[j]);
                else if (sect == 1) v =  KL2E * (bih[NHW + j] + bhh[NHW + j]);
                else if (sect == 2) v = 2.f * KL2E * bih[2 * NHW + j];
                else                v = 2.f * KL2E * bhh[2 * NHW + j];
            }
            ((float*)(blob + (size_t)(tid >> 2) * 464 + 448))[tid & 3] = v;
        }
    } else {
        const int cb = lb - 14;
        const float* W  = word ? waW : saW;
        const float* ab = word ? wab : sab;
        const float* cx = word ? wactx : sactx;
        for (int e = tid; e < 48 * 200; e += 256) {
            const int row = e / 200, k = e - row * 200;
            const int d = cb * 48 + row;
            if (d < FEAT) w16[row * 232 + k] = f2bf(W[(size_t)d * FEAT + k]);
        }
        if (tid < 48) {
            const int d = cb * 48 + tid;
            float ab2 = 0.f, cxn = 0.f;
            if (d < FEAT) { ab2 = 2.f * KL2E * ab[d]; cxn = -2.f * cx[d]; }
            ((float*)(blob + (size_t)(tid >> 2) * 464 + 448))[tid & 3] = ab2;
            ((float*)(blob + (size_t)(12 + (tid >> 2)) * 464 + 448))[tid & 3] = cxn;
        }
    }
}

// ============================ fused HAN stage kernel =======================
// Block = 4 groups (sentences/docs), 512 thr = 8 waves (2 per group, Mt=2).
// GRU: A-frags from global (WORD: fp32 emb gather + in-reg bf16 cvt; else
// bf16 rows); B blobs double-buffered in LDS; h written to LDS H (per-wave
// rows, stride 416, conflict-free). Attn: A-frags re-read from LDS H, score
// MFMA + exp2-folded tanh*ctx, d-reduce via shfl, per-group softmax, pooling
// straight from the A-frags (shfl-reduce over d-lanes). Out = pooled bf16.
template<bool WORD>
__global__ __launch_bounds__(512, 2) void han_kernel(
    const int* __restrict__ xtok,
    const void* __restrict__ Ain,
    const char* __restrict__ gpk,    // 14 GRU blobs
    const char* __restrict__ apk,    // 5 attn blobs
    const int nvalid,                // 50 / 40
    unsigned short* __restrict__ Out)
{
    __shared__ __align__(16) char smem[160256];
    char*  Hsh   = smem;                          // [4][64][416]
    char*  bufs  = smem + 106496;                 // 2 x 22272
    float* sc_sh = (float*)(smem + 151040);       // [4][64]
    float* al_sh = (float*)(smem + 152064);       // [4][64]
    float* part  = (float*)(smem + 153088);       // [4][2][224]

    const int tid  = threadIdx.x;
    const int lane = tid & 63, wv = tid >> 6;
    const int sent = wv >> 1, half = wv & 1;
    const int ln15 = lane & 15, q = lane >> 4;
    const long g   = (long)blockIdx.x * 4 + sent;
    char* Hme = Hsh + (size_t)sent * 26624;

    // ---- A fragments ----
    bf16x8 af[2][7];
    if (WORD) {
        const float* emb = (const float*)Ain;
        #pragma unroll
        for (int Mt = 0; Mt < 2; ++Mt) {
            const int item = half * 32 + Mt * 16 + ln15;
            int tok = VOCABM1;                       // padding row: all zeros
            if (item < nvalid) tok = xtok[g * nvalid + item];
            const float4* rp = (const float4*)(emb + (long)tok * ED);
            #pragma unroll
            for (int kc = 0; kc < 6; ++kc)
                af[Mt][kc] = pack8(rp[kc * 8 + q * 2], rp[kc * 8 + q * 2 + 1]);
            af[Mt][6] = (q == 0) ? pack8(rp[48], rp[49]) : (bf16x8)(short)0;
        }
    } else {
        const char* sv = (const char*)Ain;
        #pragma unroll
        for (int Mt = 0; Mt < 2; ++Mt) {
            const int item = half * 32 + Mt * 16 + ln15;
            const int ic = item < nvalid ? item : nvalid - 1;
            const char* rp = sv + (g * nvalid + ic) * 400;
            #pragma unroll
            for (int kc = 0; kc < 7; ++kc) {
                bf16x8 v = (bf16x8)(short)0;
                if (item < nvalid && (kc < 6 || q == 0))
                    v = *(const bf16x8*)(rp + kc * 64 + q * 16);
                af[Mt][kc] = v;
            }
        }
    }

    stageBlob(bufs, gpk, tid);
    __syncthreads();

    bf16x8 hf[2][7];
    float sacc[2][4] = {{0.f}};

    for (int s = 0; s < 19; ++s) {
        char* cur = bufs + (size_t)(s & 1) * BB;
        if (s + 1 < 19) {
            const char* nb = (s + 1 < 14) ? gpk + (size_t)(s + 1) * BB
                                          : apk + (size_t)(s + 1 - 14) * BB;
            stageBlob(bufs + (size_t)((s + 1) & 1) * BB, nb, tid);
        }

        if (s < 14) {
            // ---- GRU chunk: units [cc*16, +16) of direction dir ----
            f32x4 a0[2] = {}, a1[2] = {}, a2[2] = {};
            #pragma unroll
            for (int kc = 0; kc < 7; ++kc) {
                const bf16x8 b0 = *(const bf16x8*)(cur + (size_t)(0  + ln15) * 464 + kc * 64 + q * 16);
                const bf16x8 b1 = *(const bf16x8*)(cur + (size_t)(16 + ln15) * 464 + kc * 64 + q * 16);
                const bf16x8 b2 = *(const bf16x8*)(cur + (size_t)(32 + ln15) * 464 + kc * 64 + q * 16);
                #pragma unroll
                for (int Mt = 0; Mt < 2; ++Mt) {
                    a0[Mt] = __builtin_amdgcn_mfma_f32_16x16x32_bf16(b0, af[Mt][kc], a0[Mt], 0, 0, 0);
                    a1[Mt] = __builtin_amdgcn_mfma_f32_16x16x32_bf16(b1, af[Mt][kc], a1[Mt], 0, 0, 0);
                    a2[Mt] = __builtin_amdgcn_mfma_f32_16x16x32_bf16(b2, af[Mt][kc], a2[Mt], 0, 0, 0);
                }
            }
            const int dir = s / 7, cc = s - dir * 7;
            if (cc * 16 + q * 4 < NHW) {
                const f32x4 bR = *(const f32x4*)(cur + (size_t)(0  + q) * 464 + 448);
                const f32x4 bZ = *(const f32x4*)(cur + (size_t)(4  + q) * 464 + 448);
                const f32x4 bN = *(const f32x4*)(cur + (size_t)(8  + q) * 464 + 448);
                const f32x4 hN = *(const f32x4*)(cur + (size_t)(12 + q) * 464 + 448);
                const int ub = dir * NHW + cc * 16 + q * 4;
                #pragma unroll
                for (int Mt = 0; Mt < 2; ++Mt) {
                    float h[4];
                    #pragma unroll
                    for (int rg = 0; rg < 4; ++rg) {
                        const float r  = frcp(1.f + fexp2(fmaf(a0[Mt][rg], -KL2E, bR[rg])));
                        const float zc = frcp(1.f + fexp2(fmaf(a1[Mt][rg],  KL2E, bZ[rg])));
                        const float t  = frcp(1.f + fexp2(fmaf(a2[Mt][rg], 2.f * KL2E,
                                                  fmaf(r, hN[rg], bN[rg]))));
                        h[rg] = zc * (1.f - 2.f * t);
                    }
                    uint2 o; o.x = pk2(h[0], h[1]); o.y = pk2(h[2], h[3]);
                    *(uint2*)(Hme + (size_t)(half * 32 + Mt * 16 + ln15) * 416 + ub * 2) = o;
                }
            }
        } else {
            // ---- attention score chunk ----
            if (s == 14) {   // H complete (sync at end of s=13); rows wave-own
                #pragma unroll
                for (int Mt = 0; Mt < 2; ++Mt)
                    #pragma unroll
                    for (int kc = 0; kc < 7; ++kc) {
                        bf16x8 v = (bf16x8)(short)0;
                        if (kc < 6 || q == 0)
                            v = *(const bf16x8*)(Hme + (size_t)(half * 32 + Mt * 16 + ln15) * 416
                                                 + kc * 64 + q * 16);
                        hf[Mt][kc] = v;
                    }
            }
            f32x4 ac[2][3] = {};
            #pragma unroll
            for (int kc = 0; kc < 7; ++kc) {
                const bf16x8 b0 = *(const bf16x8*)(cur + (size_t)(0  + ln15) * 464 + kc * 64 + q * 16);
                const bf16x8 b1 = *(const bf16x8*)(cur + (size_t)(16 + ln15) * 464 + kc * 64 + q * 16);
                const bf16x8 b2 = *(const bf16x8*)(cur + (size_t)(32 + ln15) * 464 + kc * 64 + q * 16);
                #pragma unroll
                for (int Mt = 0; Mt < 2; ++Mt) {
                    ac[Mt][0] = __builtin_amdgcn_mfma_f32_16x16x32_bf16(hf[Mt][kc], b0, ac[Mt][0], 0, 0, 0);
                    ac[Mt][1] = __builtin_amdgcn_mfma_f32_16x16x32_bf16(hf[Mt][kc], b1, ac[Mt][1], 0, 0, 0);
                    ac[Mt][2] = __builtin_amdgcn_mfma_f32_16x16x32_bf16(hf[Mt][kc], b2, ac[Mt][2], 0, 0, 0);
                }
            }
            // tanh(u)·cx = cx - 2·cx·sig-like; constant Σcx dropped (softmax-
            // shift-invariant): sacc += u * cx2n, u = 1/(1+exp2(2K·acc + ab2))
            #pragma unroll
            for (int Nt = 0; Nt < 3; ++Nt) {
                const int bo = 4 * (Nt * 16 + ln15);
                const float ab2 = *(const float*)(cur + (size_t)(bo >> 4) * 464 + 448 + (bo & 15));
                const int co = 192 + bo;
                const float cxn = *(const float*)(cur + (size_t)(co >> 4) * 464 + 448 + (co & 15));
                #pragma unroll
                for (int Mt = 0; Mt < 2; ++Mt)
                    #pragma unroll
                    for (int rg = 0; rg < 4; ++rg) {
                        const float u = frcp(1.f + fexp2(fmaf(ac[Mt][Nt][rg], 2.f * KL2E, ab2)));
                        sacc[Mt][rg] = fmaf(u, cxn, sacc[Mt][rg]);
                    }
            }
        }
        __syncthreads();
    }

    // ---- reduce scores over the 16 d-lanes; park per word-row ----
    #pragma unroll
    for (int Mt = 0; Mt < 2; ++Mt)
        #pragma unroll
        for (int rg = 0; rg < 4; ++rg) {
            float v = sacc[Mt][rg];
            v += __shfl_xor(v, 1); v += __shfl_xor(v, 2);
            v += __shfl_xor(v, 4); v += __shfl_xor(v, 8);
            sacc[Mt][rg] = v;
        }
    if (ln15 == 0) {
        #pragma unroll
        for (int Mt = 0; Mt < 2; ++Mt)
            #pragma unroll
            for (int rg = 0; rg < 4; ++rg)
                sc_sh[sent * 64 + half * 32 + Mt * 16 + q * 4 + rg] = sacc[Mt][rg];
    }
    __syncthreads();

    // ---- per-group softmax over 64 padded rows (exp2-scaled) ----
    {
        const float sv0 = (lane < nvalid) ? sc_sh[sent * 64 + lane] : -1e30f;
        float m = sv0;
        m = fmaxf(m, __shfl_xor(m, 1));  m = fmaxf(m, __shfl_xor(m, 2));
        m = fmaxf(m, __shfl_xor(m, 4));  m = fmaxf(m, __shfl_xor(m, 8));
        m = fmaxf(m, __shfl_xor(m, 16)); m = fmaxf(m, __shfl_xor(m, 32));
        const float e = (lane < nvalid) ? fexp2((sv0 - m) * KL2E) : 0.f;
        float ss = e;
        ss += __shfl_xor(ss, 1);  ss += __shfl_xor(ss, 2);
        ss += __shfl_xor(ss, 4);  ss += __shfl_xor(ss, 8);
        ss += __shfl_xor(ss, 16); ss += __shfl_xor(ss, 32);
        if (half == 0) al_sh[sent * 64 + lane] = e * frcp(ss);
    }
    __syncthreads();

    // ---- pooling straight from hf fragments ----
    {
        const float aM0 = al_sh[sent * 64 + half * 32 + ln15];
        const float aM1 = al_sh[sent * 64 + half * 32 + 16 + ln15];
        #pragma unroll
        for (int kc = 0; kc < 7; ++kc) {
            float p[8];
            #pragma unroll
            for (int j = 0; j < 8; ++j)
                p[j] = aM0 * bf2f(hf[0][kc][j]) + aM1 * bf2f(hf[1][kc][j]);
            #pragma unroll
            for (int j = 0; j < 8; ++j) {
                p[j] += __shfl_xor(p[j], 1); p[j] += __shfl_xor(p[j], 2);
                p[j] += __shfl_xor(p[j], 4); p[j] += __shfl_xor(p[j], 8);
            }
            if (ln15 == 0) {
                float* dst = part + (size_t)(sent * 2 + half) * 224 + kc * 32 + q * 8;
                f32x4 v0 = {p[0], p[1], p[2], p[3]};
                f32x4 v1 = {p[4], p[5], p[6], p[7]};
                *(f32x4*)dst = v0; *(f32x4*)(dst + 4) = v1;
            }
        }
    }
    __syncthreads();

    // ---- combine halves, write pooled bf16 rows ----
    if (tid < 200) {
        const int sl = tid / 50, i = tid - sl * 50;     // i*4 = k0 < 200
        const float* pa = part + (size_t)(sl * 2) * 224 + i * 4;
        const float* pb = part + (size_t)(sl * 2 + 1) * 224 + i * 4;
        uint2 o;
        o.x = pk2(pa[0] + pb[0], pa[1] + pb[1]);
        o.y = pk2(pa[2] + pb[2], pa[3] + pb[3]);
        *(uint2*)(Out + ((long)blockIdx.x * 4 + sl) * 200 + i * 4) = o;
    }
}

// ============================ classifier + log_softmax =====================
__global__ void cls_kernel(const unsigned short* __restrict__ dvec,
                           const float* __restrict__ fcW, const float* __restrict__ fcb,
                           float* __restrict__ out)
{
    const int doc = blockIdx.x, lane = threadIdx.x;  // 64 threads
    const int c = lane & 15, part = lane >> 4;
    const int cs = (c < NC) ? c : 0;
    float acc = (part == 0 && c < NC) ? fcb[c] : 0.f;
    for (int i = 0; i < 50; ++i) {
        const int k = part * 50 + i;
        const float a = bf2f((short)dvec[(size_t)doc * 200 + k]);
        acc += a * ((c < NC) ? fcW[(size_t)cs * 200 + k] : 0.f);
    }
    acc += __shfl_xor(acc, 16); acc += __shfl_xor(acc, 32);
    const float lg = (c < NC) ? acc : -1e30f;
    float m = lg;
    m = fmaxf(m, __shfl_xor(m, 1)); m = fmaxf(m, __shfl_xor(m, 2));
    m = fmaxf(m, __shfl_xor(m, 4)); m = fmaxf(m, __shfl_xor(m, 8));
    const float e = (c < NC) ? __expf(lg - m) : 0.f;
    float ss = e;
    ss += __shfl_xor(ss, 1); ss += __shfl_xor(ss, 2);
    ss += __shfl_xor(ss, 4); ss += __shfl_xor(ss, 8);
    const float lse = m + __logf(ss);
    if (lane < NC) out[(size_t)doc * NC + lane] = lg - lse;
}

// ======================================================================
// Fallback fp32 path — used only if ws_size < WS_NEED.
// ======================================================================
template<int NWRD, int WT>
__device__ __forceinline__ void encode_block(
    float* __restrict__ e_sh, float* __restrict__ h_sh, float* __restrict__ sc_sh,
    const float* __restrict__ Wf, const float* __restrict__ bihf, const float* __restrict__ bhhf,
    const float* __restrict__ Wb, const float* __restrict__ bihb, const float* __restrict__ bhhb,
    const float* __restrict__ aW, const float* __restrict__ ab, const float* __restrict__ actx,
    int tid)
{
    constexpr int WG = NWRD / WT;
    for (int item = tid; item < FEAT * WG; item += 256) {
        const int unit = item % FEAT, wg = item / FEAT;
        const int dir = unit / NHW, j = unit - dir * NHW;
        const float* Wd  = dir ? Wb : Wf;
        const float* bih = dir ? bihb : bihf;
        const float* bhh = dir ? bhhb : bhhf;
        const float4* rowR = (const float4*)(Wd + (size_t)j * ED);
        const float4* rowZ = (const float4*)(Wd + (size_t)(NHW + j) * ED);
        const float4* rowN = (const float4*)(Wd + (size_t)(2 * NHW + j) * ED);
        float aR[WT], aZ[WT], aN[WT];
        #pragma unroll
        for (int t = 0; t < WT; ++t) { aR[t] = 0.f; aZ[t] = 0.f; aN[t] = 0.f; }
        const int w0 = wg * WT;
        #pragma unroll 1
        for (int k4 = 0; k4 < ED / 4; ++k4) {
            const float4 wr = rowR[k4], wz = rowZ[k4], wn = rowN[k4];
            #pragma unroll
            for (int t = 0; t < WT; ++t) {
                const float4 e = *(const float4*)(e_sh + (w0 + t) * ED + k4 * 4);
                aR[t] += wr.x*e.x + wr.y*e.y + wr.z*e.z + wr.w*e.w;
                aZ[t] += wz.x*e.x + wz.y*e.y + wz.z*e.z + wz.w*e.w;
                aN[t] += wn.x*e.x + wn.y*e.y + wn.z*e.z + wn.w*e.w;
            }
        }
        const float bR = bih[j] + bhh[j], bZ = bih[NHW+j] + bhh[NHW+j];
        const float bN = bih[2*NHW+j], hN = bhh[2*NHW+j];
        #pragma unroll
        for (int t = 0; t < WT; ++t) {
            const float r = fsig(aR[t] + bR), z = fsig(aZ[t] + bZ);
            const float n = ftanh(aN[t] + bN + r * hN);
            h_sh[(w0 + t) * FEAT + unit] = (1.f - z) * n;
        }
    }
    __syncthreads();
    for (int item = tid; item < FEAT * WG; item += 256) {
        const int d = item % FEAT, wg = item / FEAT;
        const float4* row = (const float4*)(aW + (size_t)d * FEAT);
        float acc[WT];
        #pragma unroll
        for (int t = 0; t < WT; ++t) acc[t] = 0.f;
        const int w0 = wg * WT;
        #pragma unroll 1
        for (int k4 = 0; k4 < FEAT / 4; ++k4) {
            const float4 wv = row[k4];
            #pragma unroll
            for (int t = 0; t < WT; ++t) {
                const float4 h = *(const float4*)(h_sh + (w0 + t) * FEAT + k4 * 4);
                acc[t] += wv.x*h.x + wv.y*h.y + wv.z*h.z + wv.w*h.w;
            }
        }
        const float bb = ab[d], cc = actx[d];
        #pragma unroll
        for (int t = 0; t < WT; ++t)
            e_sh[d * NWRD + (w0 + t)] = ftanh(acc[t] + bb) * cc;
    }
    __syncthreads();
    if (tid < NWRD) {
        float s = 0.f;
        for (int d = 0; d < FEAT; ++d) s += e_sh[d * NWRD + tid];
        sc_sh[tid] = s;
    }
    __syncthreads();
    if (tid == 0) {
        float m = -1e30f;
        for (int w = 0; w < NWRD; ++w) m = fmaxf(m, sc_sh[w]);
        float s = 0.f;
        for (int w = 0; w < NWRD; ++w) { const float ev = __expf(sc_sh[w] - m); sc_sh[w] = ev; s += ev; }
        const float inv = 1.f / s;
        for (int w = 0; w < NWRD; ++w) sc_sh[w] *= inv;
    }
    __syncthreads();
}

__global__ __launch_bounds__(256) void word_kernel_f32(
    const int* __restrict__ x, const float* __restrict__ emb,
    const float* __restrict__ Wf, const float* __restrict__ bihf, const float* __restrict__ bhhf,
    const float* __restrict__ Wb, const float* __restrict__ bihb, const float* __restrict__ bhhb,
    const float* __restrict__ waW, const float* __restrict__ wab, const float* __restrict__ wactx,
    float* __restrict__ svec)
{
    __shared__ __align__(16) float e_sh[NW * ED];
    __shared__ __align__(16) float h_sh[NW * FEAT];
    __shared__ float sc_sh[NW];
    const int sent = blockIdx.x, tid = threadIdx.x;
    const int* xr = x + (size_t)sent * NW;
    for (int i = tid * 4; i < NW * ED; i += 256 * 4) {
        const int w = i / ED, k = i - w * ED;
        *(float4*)(e_sh + i) = *(const float4*)(emb + (size_t)xr[w] * ED + k);
    }
    __syncthreads();
    encode_block<NW, 25>(e_sh, h_sh, sc_sh, Wf, bihf, bhhf, Wb, bihb, bhhb, waW, wab, wactx, tid);
    if (tid < FEAT) {
        float a = 0.f;
        #pragma unroll 1
        for (int w = 0; w < NW; ++w) a += sc_sh[w] * h_sh[w * FEAT + tid];
        svec[(size_t)sent * FEAT + tid] = a;
    }
}

__global__ __launch_bounds__(256) void sent_kernel_f32(
    const float* __restrict__ svec,
    const float* __restrict__ Wf, const float* __restrict__ bihf, const float* __restrict__ bhhf,
    const float* __restrict__ Wb, const float* __restrict__ bihb, const float* __restrict__ bhhb,
    const float* __restrict__ saW, const float* __restrict__ sab, const float* __restrict__ sactx,
    const float* __restrict__ fcW, const float* __restrict__ fcb,
    float* __restrict__ out)
{
    __shared__ __align__(16) float e_sh[NS * ED];
    __shared__ __align__(16) float h_sh[NS * FEAT];
    __shared__ float sc_sh[NS];
    __shared__ float dvec_sh[FEAT];
    __shared__ float logit_sh[NC];
    __shared__ float lse_sh;
    const int b = blockIdx.x, tid = threadIdx.x;
    const float* src = svec + (size_t)b * NS * FEAT;
    for (int i = tid * 4; i < NS * FEAT; i += 256 * 4)
        *(float4*)(e_sh + i) = *(const float4*)(src + i);
    __syncthreads();
    encode_block<NS, 20>(e_sh, h_sh, sc_sh, Wf, bihf, bhhf, Wb, bihb, bhhb, saW, sab, sactx, tid);
    if (tid < FEAT) {
        float a = 0.f;
        #pragma unroll 1
        for (int s = 0; s < NS; ++s) a += sc_sh[s] * h_sh[s * FEAT + tid];
        dvec_sh[tid] = a;
    }
    __syncthreads();
    if (tid < NC) {
        float a = fcb[tid];
        const float* row = fcW + (size_t)tid * FEAT;
        for (int k = 0; k < FEAT; ++k) a += row[k] * dvec_sh[k];
        logit_sh[tid] = a;
    }
    __syncthreads();
    if (tid == 0) {
        float m = -1e30f;
        for (int c = 0; c < NC; ++c) m = fmaxf(m, logit_sh[c]);
        float s = 0.f;
        for (int c = 0; c < NC; ++c) s += __expf(logit_sh[c] - m);
        lse_sh = m + logf(s);
    }
    __syncthreads();
    if (tid < NC) out[(size_t)b * NC + tid] = logit_sh[tid] - lse_sh;
}

// ============================ launch =======================================
extern "C" void kernel_launch(void* const* d_in, const int* in_sizes, int n_in,
                              void* d_out, int out_size, void* d_ws, size_t ws_size,
                              hipStream_t stream)
{
    const int*   x     = (const int*)d_in[0];
    const float* emb   = (const float*)d_in[1];
    const float* wWf   = (const float*)d_in[2];
    const float* wbif  = (const float*)d_in[3];
    const float* wbhf  = (const float*)d_in[4];
    const float* wWb   = (const float*)d_in[5];
    const float* wbib  = (const float*)d_in[6];
    const float* wbhb  = (const float*)d_in[7];
    const float* waW   = (const float*)d_in[8];
    const float* wab   = (const float*)d_in[9];
    const float* wactx = (const float*)d_in[10];
    const float* sWf   = (const float*)d_in[11];
    const float* sbif  = (const float*)d_in[12];
    const float* sbhf  = (const float*)d_in[13];
    const float* sWb   = (const float*)d_in[14];
    const float* sbib  = (const float*)d_in[15];
    const float* sbhb  = (const float*)d_in[16];
    const float* saW   = (const float*)d_in[17];
    const float* sab   = (const float*)d_in[18];
    const float* sactx = (const float*)d_in[19];
    const float* fcW   = (const float*)d_in[20];
    const float* fcb   = (const float*)d_in[21];
    float* out = (float*)d_out;

    if (ws_size < WS_NEED) {
        float* svec = (float*)d_ws;
        word_kernel_f32<<<NB * NS, 256, 0, stream>>>(
            x, emb, wWf, wbif, wbhf, wWb, wbib, wbhb, waW, wab, wactx, svec);
        sent_kernel_f32<<<NB, 256, 0, stream>>>(
            svec, sWf, sbif, sbhf, sWb, sbib, sbhb, saW, sab, sactx, fcW, fcb, out);
        return;
    }

    char* ws = (char*)d_ws;
    unsigned short* svec = (unsigned short*)(ws + OFF_SV);
    unsigned short* dvec = (unsigned short*)(ws + OFF_DV);

    pack_kernel<<<38, 256, 0, stream>>>(
        wWf, wbif, wbhf, wWb, wbib, wbhb, waW, wab, wactx,
        sWf, sbif, sbhf, sWb, sbib, sbhb, saW, sab, sactx, ws);

    // word stage: 5120 sentences / 4 per block
    han_kernel<true><<<NB * NS / 4, 512, 0, stream>>>(
        x, emb, ws + OFF_PGW, ws + OFF_PAW, NW, svec);

    // sentence stage: 128 docs / 4 per block
    han_kernel<false><<<NB / 4, 512, 0, stream>>>(
        nullptr, svec, ws + OFF_PGS, ws + OFF_PAS, NS, dvec);

    cls_kernel<<<NB, 64, 0, stream>>>(dvec, fcW, fcb, out);
}